// Round 1
// baseline (4357.085 us; speedup 1.0000x reference)
//
#include <hip/hip_runtime.h>

// ---------------------------------------------------------------------------
// Two-layer GCN on MI355X.  Baseline round: fp32 LDS-tiled GEMM + atomic
// edge scatter.  Layout:
//   deg/dinv  : N floats   (in-place: deg -> rsqrt(deg+1))
//   norm      : E floats   (dinv[src]*ew*dinv[dst], shared by both layers)
//   h         : N*128      (h1 = x@W1, later overwritten with relu(out1))
//   agg       : N*128      (agg1, later reused for agg2)
//   h2        : N*64       (h2 = out1@W2)
// ---------------------------------------------------------------------------

#define N_NODES 100000
#define K_DIM   128

__global__ __launch_bounds__(256) void deg_kernel(
    const int* __restrict__ dst, const float* __restrict__ ew,
    float* __restrict__ deg, int E)
{
    int e = blockIdx.x * 256 + threadIdx.x;
    if (e < E) atomicAdd(&deg[dst[e]], ew[e]);
}

__global__ __launch_bounds__(256) void rsqrt_kernel(float* __restrict__ d, int N)
{
    int i = blockIdx.x * 256 + threadIdx.x;
    if (i < N) d[i] = rsqrtf(d[i] + 1.0f);
}

__global__ __launch_bounds__(256) void norm_kernel(
    const int* __restrict__ src, const int* __restrict__ dst,
    const float* __restrict__ ew, const float* __restrict__ dinv,
    float* __restrict__ norm, int E)
{
    int e = blockIdx.x * 256 + threadIdx.x;
    if (e < E) norm[e] = dinv[src[e]] * ew[e] * dinv[dst[e]];
}

// H = X @ W  (X: M x 128, W: 128 x NCOL), also AGG = H * dinv^2 (self-loop init).
// Block: 256 threads, 64 rows, K-tiles of 32.
// Thread (tg, tx): 2 cols (2*tx, 2*tx+1) x RPT rows.  X reads are wave-uniform
// broadcasts; W reads are ds_read_b64 (2-way aliasing = free).
template <int NCOL>
__global__ __launch_bounds__(256) void gemm_kernel(
    const float* __restrict__ X, const float* __restrict__ W,
    const float* __restrict__ dinv,
    float* __restrict__ H, float* __restrict__ AGG, int M)
{
    constexpr int K    = 128;
    constexpr int KT   = 32;
    constexpr int ROWS = 64;
    constexpr int GX   = NCOL / 2;    // threads across cols
    constexpr int NG   = 256 / GX;    // row groups
    constexpr int RPT  = ROWS / NG;   // rows per thread

    __shared__ float sX[ROWS][KT + 4];   // stride 36 floats = 144 B (16B aligned)
    __shared__ float sW[KT][NCOL];

    const int tid   = threadIdx.x;
    const int tx    = tid % GX;
    const int tg    = tid / GX;
    const int rbase = blockIdx.x * ROWS;

    float acc[RPT][2];
#pragma unroll
    for (int r = 0; r < RPT; ++r) { acc[r][0] = 0.f; acc[r][1] = 0.f; }

    for (int kb = 0; kb < K; kb += KT) {
        // ---- stage X tile (ROWS x KT) ----
#pragma unroll
        for (int it = 0; it < (ROWS * KT / 4) / 256; ++it) {
            int fq  = tid + it * 256;
            int row = fq / (KT / 4);
            int kc  = fq % (KT / 4);
            int gr  = rbase + row;
            float4 v = make_float4(0.f, 0.f, 0.f, 0.f);
            if (gr < M) v = *(const float4*)&X[gr * K + kb + kc * 4];
            *(float4*)&sX[row][kc * 4] = v;
        }
        // ---- stage W tile (KT x NCOL) ----
#pragma unroll
        for (int it = 0; it < (KT * NCOL / 4) / 256; ++it) {
            int fq = tid + it * 256;
            int k  = fq / (NCOL / 4);
            int c  = fq % (NCOL / 4);
            *(float4*)&sW[k][c * 4] = *(const float4*)&W[(kb + k) * NCOL + c * 4];
        }
        __syncthreads();

#pragma unroll
        for (int kc = 0; kc < KT; kc += 4) {
            float2 w0 = *(float2*)&sW[kc + 0][2 * tx];
            float2 w1 = *(float2*)&sW[kc + 1][2 * tx];
            float2 w2 = *(float2*)&sW[kc + 2][2 * tx];
            float2 w3 = *(float2*)&sW[kc + 3][2 * tx];
#pragma unroll
            for (int r = 0; r < RPT; ++r) {
                float4 xv = *(float4*)&sX[tg * RPT + r][kc];
                acc[r][0] = fmaf(xv.x, w0.x, acc[r][0]);
                acc[r][1] = fmaf(xv.x, w0.y, acc[r][1]);
                acc[r][0] = fmaf(xv.y, w1.x, acc[r][0]);
                acc[r][1] = fmaf(xv.y, w1.y, acc[r][1]);
                acc[r][0] = fmaf(xv.z, w2.x, acc[r][0]);
                acc[r][1] = fmaf(xv.z, w2.y, acc[r][1]);
                acc[r][0] = fmaf(xv.w, w3.x, acc[r][0]);
                acc[r][1] = fmaf(xv.w, w3.y, acc[r][1]);
            }
        }
        __syncthreads();
    }

#pragma unroll
    for (int r = 0; r < RPT; ++r) {
        int gr = rbase + tg * RPT + r;
        if (gr < M) {
            float di = dinv[gr];
            float d2 = di * di;
            float2 hv = make_float2(acc[r][0], acc[r][1]);
            *(float2*)&H[gr * NCOL + 2 * tx]   = hv;
            float2 av = make_float2(hv.x * d2, hv.y * d2);
            *(float2*)&AGG[gr * NCOL + 2 * tx] = av;
        }
    }
}

// AGG[dst] += H[src] * norm  over edges; C/4 threads per edge, float4 gather,
// 4x global_atomic_add_f32 scatter.
template <int C>
__global__ __launch_bounds__(256) void scatter_kernel(
    const int* __restrict__ src, const int* __restrict__ dst,
    const float* __restrict__ norm, const float* __restrict__ H,
    float* __restrict__ AGG, int E)
{
    constexpr int TPE = C / 4;
    int i = blockIdx.x * 256 + threadIdx.x;
    int e = i / TPE;
    if (e >= E) return;
    int c = (i % TPE) * 4;
    int s = src[e], d = dst[e];
    float nv = norm[e];
    float4 hv = *(const float4*)&H[s * C + c];
    float* ap = &AGG[d * C + c];
    atomicAdd(ap + 0, hv.x * nv);
    atomicAdd(ap + 1, hv.y * nv);
    atomicAdd(ap + 2, hv.z * nv);
    atomicAdd(ap + 3, hv.w * nv);
}

// OUT = (RELU ? max(AGG + b, 0) : AGG + b), float4-wide.
template <int C, bool RELU>
__global__ __launch_bounds__(256) void finish_kernel(
    const float* __restrict__ AGG, const float* __restrict__ bias,
    float* __restrict__ OUT, int N)
{
    int i = blockIdx.x * 256 + threadIdx.x;   // float4 index
    if (i >= N * (C / 4)) return;
    int c = (i % (C / 4)) * 4;
    float4 v = *(const float4*)&AGG[i * 4];
    float4 b = *(const float4*)&bias[c];
    v.x += b.x; v.y += b.y; v.z += b.z; v.w += b.w;
    if (RELU) {
        v.x = fmaxf(v.x, 0.f); v.y = fmaxf(v.y, 0.f);
        v.z = fmaxf(v.z, 0.f); v.w = fmaxf(v.w, 0.f);
    }
    *(float4*)&OUT[i * 4] = v;
}

static inline size_t align_up(size_t x) { return (x + 255) & ~size_t(255); }

extern "C" void kernel_launch(void* const* d_in, const int* in_sizes, int n_in,
                              void* d_out, int out_size, void* d_ws, size_t ws_size,
                              hipStream_t stream)
{
    const float* x  = (const float*)d_in[0];
    const int*   ei = (const int*)d_in[1];
    const float* ew = (const float*)d_in[2];
    const float* W1 = (const float*)d_in[3];
    const float* b1 = (const float*)d_in[4];
    const float* W2 = (const float*)d_in[5];
    const float* b2 = (const float*)d_in[6];
    float* out = (float*)d_out;

    const int N  = N_NODES;
    const int E  = in_sizes[2];
    const int C1 = 128, C2 = 64;
    const int* src = ei;
    const int* dst = ei + E;

    char* ws = (char*)d_ws;
    float* dinv = (float*)ws; ws += align_up((size_t)N * 4);
    float* norm = (float*)ws; ws += align_up((size_t)E * 4);
    float* h    = (float*)ws; ws += align_up((size_t)N * C1 * 4);
    float* agg  = (float*)ws; ws += align_up((size_t)N * C1 * 4);
    float* h2   = (float*)ws; ws += align_up((size_t)N * C2 * 4);

    // deg -> dinv (in-place), norm per edge
    hipMemsetAsync(dinv, 0, (size_t)N * 4, stream);
    deg_kernel<<<(E + 255) / 256, 256, 0, stream>>>(dst, ew, dinv, E);
    rsqrt_kernel<<<(N + 255) / 256, 256, 0, stream>>>(dinv, N);
    norm_kernel<<<(E + 255) / 256, 256, 0, stream>>>(src, dst, ew, dinv, norm, E);

    // ---- layer 1 ----
    gemm_kernel<128><<<(N + 63) / 64, 256, 0, stream>>>(x, W1, dinv, h, agg, N);
    scatter_kernel<128><<<((long long)E * 32 + 255) / 256, 256, 0, stream>>>(
        src, dst, norm, h, agg, E);
    finish_kernel<128, true><<<(N * 32 + 255) / 256, 256, 0, stream>>>(agg, b1, h, N);

    // ---- layer 2 ----
    gemm_kernel<64><<<(N + 63) / 64, 256, 0, stream>>>(h, W2, dinv, h2, agg, N);
    scatter_kernel<64><<<((long long)E * 16 + 255) / 256, 256, 0, stream>>>(
        src, dst, norm, h2, agg, E);
    finish_kernel<64, false><<<(N * 16 + 255) / 256, 256, 0, stream>>>(agg, b2, out, N);
}

// Round 2
// 668.334 us; speedup vs baseline: 6.5193x; 6.5193x over previous
//
#include <hip/hip_runtime.h>

// ---------------------------------------------------------------------------
// Two-layer GCN on MI355X.  Round 2: replace atomic edge-scatter with
// CSR-by-dst build (counting sort) + register-accumulating gather.
// Gather fuses self-loop, bias, and ReLU -> no agg buffer, no finish kernel.
// ---------------------------------------------------------------------------

#define N_NODES 100000

// ---- degree / norm prep ---------------------------------------------------

__global__ __launch_bounds__(256) void wdeg_kernel(
    const int* __restrict__ dst, const float* __restrict__ ew,
    float* __restrict__ deg, int E)
{
    int e = blockIdx.x * 256 + threadIdx.x;
    if (e < E) atomicAdd(&deg[dst[e]], ew[e]);
}

__global__ __launch_bounds__(256) void rsqrt_kernel(float* __restrict__ d, int N)
{
    int i = blockIdx.x * 256 + threadIdx.x;
    if (i < N) d[i] = rsqrtf(d[i] + 1.0f);
}

// ---- CSR build: count -> scan -> fill ------------------------------------

__global__ __launch_bounds__(256) void count_kernel(
    const int* __restrict__ dst, int* __restrict__ cnt, int E)
{
    int e = blockIdx.x * 256 + threadIdx.x;
    if (e < E) atomicAdd(&cnt[dst[e]], 1);
}

__global__ __launch_bounds__(256) void scan1_kernel(
    const int* __restrict__ cnt, int* __restrict__ rowStart,
    int* __restrict__ blockSums, int N)
{
    __shared__ int tmp[256];
    int t = threadIdx.x;
    int i = blockIdx.x * 256 + t;
    int v = (i < N) ? cnt[i] : 0;
    tmp[t] = v;
    __syncthreads();
#pragma unroll
    for (int off = 1; off < 256; off <<= 1) {
        int a = (t >= off) ? tmp[t - off] : 0;
        __syncthreads();
        tmp[t] += a;
        __syncthreads();
    }
    if (i < N) rowStart[i] = tmp[t] - v;          // exclusive (block-local)
    if (t == 255) blockSums[blockIdx.x] = tmp[255];
}

__global__ __launch_bounds__(512) void scan2_kernel(int* __restrict__ blockSums, int NB)
{
    __shared__ int tmp[512];
    int t = threadIdx.x;
    int v = (t < NB) ? blockSums[t] : 0;
    tmp[t] = v;
    __syncthreads();
#pragma unroll
    for (int off = 1; off < 512; off <<= 1) {
        int a = (t >= off) ? tmp[t - off] : 0;
        __syncthreads();
        tmp[t] += a;
        __syncthreads();
    }
    if (t < NB) blockSums[t] = tmp[t] - v;        // exclusive
}

__global__ __launch_bounds__(256) void scan3_kernel(
    int* __restrict__ rowStart, const int* __restrict__ blockSums, int N, int E)
{
    int i = blockIdx.x * 256 + threadIdx.x;
    if (i < N) rowStart[i] += blockSums[blockIdx.x];
    if (i == 0) rowStart[N] = E;
}

// fill CSR (src index + fused norm weight)
__global__ __launch_bounds__(256) void fill_kernel(
    const int* __restrict__ src, const int* __restrict__ dst,
    const float* __restrict__ ew, const float* __restrict__ dinv,
    const int* __restrict__ rowStart, int* __restrict__ cursor,
    int* __restrict__ csr_src, float* __restrict__ csr_w, int E)
{
    int e = blockIdx.x * 256 + threadIdx.x;
    if (e >= E) return;
    int s = src[e], d = dst[e];
    int pos = rowStart[d] + atomicAdd(&cursor[d], 1);
    csr_src[pos] = s;
    csr_w[pos]   = dinv[s] * ew[e] * dinv[d];
}

// ---- GEMM: H = X @ W  (X: M x 128, W: 128 x NCOL) -------------------------

template <int NCOL>
__global__ __launch_bounds__(256) void gemm_kernel(
    const float* __restrict__ X, const float* __restrict__ W,
    float* __restrict__ H, int M)
{
    constexpr int K    = 128;
    constexpr int KT   = 32;
    constexpr int ROWS = 64;
    constexpr int GX   = NCOL / 2;
    constexpr int NG   = 256 / GX;
    constexpr int RPT  = ROWS / NG;

    __shared__ float sX[ROWS][KT + 4];
    __shared__ float sW[KT][NCOL];

    const int tid   = threadIdx.x;
    const int tx    = tid % GX;
    const int tg    = tid / GX;
    const int rbase = blockIdx.x * ROWS;

    float acc[RPT][2];
#pragma unroll
    for (int r = 0; r < RPT; ++r) { acc[r][0] = 0.f; acc[r][1] = 0.f; }

    for (int kb = 0; kb < K; kb += KT) {
#pragma unroll
        for (int it = 0; it < (ROWS * KT / 4) / 256; ++it) {
            int fq  = tid + it * 256;
            int row = fq / (KT / 4);
            int kc  = fq % (KT / 4);
            int gr  = rbase + row;
            float4 v = make_float4(0.f, 0.f, 0.f, 0.f);
            if (gr < M) v = *(const float4*)&X[(size_t)gr * K + kb + kc * 4];
            *(float4*)&sX[row][kc * 4] = v;
        }
#pragma unroll
        for (int it = 0; it < (KT * NCOL / 4) / 256; ++it) {
            int fq = tid + it * 256;
            int k  = fq / (NCOL / 4);
            int c  = fq % (NCOL / 4);
            *(float4*)&sW[k][c * 4] = *(const float4*)&W[(size_t)(kb + k) * NCOL + c * 4];
        }
        __syncthreads();

#pragma unroll
        for (int kc = 0; kc < KT; kc += 4) {
            float2 w0 = *(float2*)&sW[kc + 0][2 * tx];
            float2 w1 = *(float2*)&sW[kc + 1][2 * tx];
            float2 w2 = *(float2*)&sW[kc + 2][2 * tx];
            float2 w3 = *(float2*)&sW[kc + 3][2 * tx];
#pragma unroll
            for (int r = 0; r < RPT; ++r) {
                float4 xv = *(float4*)&sX[tg * RPT + r][kc];
                acc[r][0] = fmaf(xv.x, w0.x, acc[r][0]);
                acc[r][1] = fmaf(xv.x, w0.y, acc[r][1]);
                acc[r][0] = fmaf(xv.y, w1.x, acc[r][0]);
                acc[r][1] = fmaf(xv.y, w1.y, acc[r][1]);
                acc[r][0] = fmaf(xv.z, w2.x, acc[r][0]);
                acc[r][1] = fmaf(xv.z, w2.y, acc[r][1]);
                acc[r][0] = fmaf(xv.w, w3.x, acc[r][0]);
                acc[r][1] = fmaf(xv.w, w3.y, acc[r][1]);
            }
        }
        __syncthreads();
    }

#pragma unroll
    for (int r = 0; r < RPT; ++r) {
        int gr = rbase + tg * RPT + r;
        if (gr < M)
            *(float2*)&H[(size_t)gr * NCOL + 2 * tx] = make_float2(acc[r][0], acc[r][1]);
    }
}

// ---- gather: OUT[n] = relu?( sum_{e in CSR[n]} H[src_e]*w_e + H[n]*dinv^2 + b )
// One wave per node; lane owns C/64 consecutive channels.

template <int C, bool RELU>
__global__ __launch_bounds__(256) void gather_kernel(
    const int* __restrict__ rowStart, const int* __restrict__ csr_src,
    const float* __restrict__ csr_w, const float* __restrict__ H,
    const float* __restrict__ dinv, const float* __restrict__ bias,
    float* __restrict__ OUT, int N)
{
    constexpr int VPL = C / 64;     // floats per lane (2 for C=128, 1 for C=64)
    int node = blockIdx.x * 4 + (threadIdx.x >> 6);
    if (node >= N) return;
    int lane = threadIdx.x & 63;
    int c = lane * VPL;

    float di = dinv[node];
    float d2 = di * di;
    float acc[VPL];
#pragma unroll
    for (int v = 0; v < VPL; ++v)
        acc[v] = H[(size_t)node * C + c + v] * d2;

    int beg = rowStart[node], end = rowStart[node + 1];
    for (int j = beg; j < end; j += 64) {
        int m = end - j;
        if (m > 64) m = 64;
        int   sj = 0;
        float wj = 0.f;
        if (lane < m) { sj = csr_src[j + lane]; wj = csr_w[j + lane]; }
        for (int k = 0; k < m; ++k) {
            int   s = __shfl(sj, k);
            float w = __shfl(wj, k);
            const float* hp = &H[(size_t)s * C + c];
#pragma unroll
            for (int v = 0; v < VPL; ++v)
                acc[v] = fmaf(hp[v], w, acc[v]);
        }
    }

#pragma unroll
    for (int v = 0; v < VPL; ++v) {
        float o = acc[v] + bias[c + v];
        if (RELU) o = fmaxf(o, 0.f);
        OUT[(size_t)node * C + c + v] = o;
    }
}

static inline size_t align_up(size_t x) { return (x + 255) & ~size_t(255); }

extern "C" void kernel_launch(void* const* d_in, const int* in_sizes, int n_in,
                              void* d_out, int out_size, void* d_ws, size_t ws_size,
                              hipStream_t stream)
{
    const float* x  = (const float*)d_in[0];
    const int*   ei = (const int*)d_in[1];
    const float* ew = (const float*)d_in[2];
    const float* W1 = (const float*)d_in[3];
    const float* b1 = (const float*)d_in[4];
    const float* W2 = (const float*)d_in[5];
    const float* b2 = (const float*)d_in[6];
    float* out = (float*)d_out;

    const int N = N_NODES;
    const int E = in_sizes[2];
    const int* src = ei;
    const int* dst = ei + E;

    const int NB = (N + 255) / 256;   // scan blocks (391)

    char* ws = (char*)d_ws;
    float* dinv     = (float*)ws; ws += align_up((size_t)N * 4);
    int*   rowStart = (int*)ws;   ws += align_up(((size_t)N + 1) * 4);
    int*   cnt      = (int*)ws;   ws += align_up((size_t)N * 4);       // counts, then cursor
    int*   blockSums= (int*)ws;   ws += align_up((size_t)NB * 4);
    int*   csr_src  = (int*)ws;   ws += align_up((size_t)E * 4);
    float* csr_w    = (float*)ws; ws += align_up((size_t)E * 4);
    float* h        = (float*)ws; ws += align_up((size_t)N * 128 * 4); // h1, then h2
    float* g1       = (float*)ws; ws += align_up((size_t)N * 128 * 4); // relu(conv1)

    const int EB = (E + 255) / 256;

    // degrees -> dinv
    hipMemsetAsync(dinv, 0, (size_t)N * 4, stream);
    wdeg_kernel<<<EB, 256, 0, stream>>>(dst, ew, dinv, E);
    rsqrt_kernel<<<NB, 256, 0, stream>>>(dinv, N);

    // CSR by dst
    hipMemsetAsync(cnt, 0, (size_t)N * 4, stream);
    count_kernel<<<EB, 256, 0, stream>>>(dst, cnt, E);
    scan1_kernel<<<NB, 256, 0, stream>>>(cnt, rowStart, blockSums, N);
    scan2_kernel<<<1, 512, 0, stream>>>(blockSums, NB);
    scan3_kernel<<<NB, 256, 0, stream>>>(rowStart, blockSums, N, E);
    hipMemsetAsync(cnt, 0, (size_t)N * 4, stream);   // reuse as cursor
    fill_kernel<<<EB, 256, 0, stream>>>(src, dst, ew, dinv, rowStart, cnt,
                                        csr_src, csr_w, E);

    // ---- layer 1 ----
    gemm_kernel<128><<<(N + 63) / 64, 256, 0, stream>>>(x, W1, h, N);
    gather_kernel<128, true><<<(N + 3) / 4, 256, 0, stream>>>(
        rowStart, csr_src, csr_w, h, dinv, b1, g1, N);

    // ---- layer 2 ----
    gemm_kernel<64><<<(N + 63) / 64, 256, 0, stream>>>(g1, W2, h, N);
    gather_kernel<64, false><<<(N + 3) / 4, 256, 0, stream>>>(
        rowStart, csr_src, csr_w, h, dinv, b2, out, N);
}

// Round 3
// 516.033 us; speedup vs baseline: 8.4434x; 1.2951x over previous
//
#include <hip/hip_runtime.h>

// ---------------------------------------------------------------------------
// Two-layer GCN on MI355X.  Round 3:
//   - h stored as bf16 (packed 2/dword): halves gather read traffic
//   - gather edge-loop unrolled x4 (4 row-loads in flight per wave)
//   - C=64 gather uses 32-lane sub-waves (full dword per lane)
//   - CSR interleaved as uint2 {src, w-bits}: 1 scattered store / 1 load
//   - fused deg+count edge pass; rsqrt fused into scan1; cursor from scan3
// ---------------------------------------------------------------------------

#define N_NODES 100000

__device__ __forceinline__ unsigned bf16r(float f) {
    unsigned u = __float_as_uint(f);
    return (u + 0x7fffu + ((u >> 16) & 1u)) >> 16;     // RNE
}
__device__ __forceinline__ float bf_lo(unsigned u) { return __uint_as_float(u << 16); }
__device__ __forceinline__ float bf_hi(unsigned u) { return __uint_as_float(u & 0xffff0000u); }

// ---- fused weighted-degree + count (one edge pass) ------------------------

__global__ __launch_bounds__(256) void deg_count_kernel(
    const int* __restrict__ dst, const float* __restrict__ ew,
    float* __restrict__ deg, int* __restrict__ cnt, int E)
{
    int e = blockIdx.x * 256 + threadIdx.x;
    if (e < E) {
        int d = dst[e];
        atomicAdd(&deg[d], ew[e]);
        atomicAdd(&cnt[d], 1);
    }
}

// ---- scan (block-local excl) + dinv transform -----------------------------

__global__ __launch_bounds__(256) void scan1_kernel(
    const int* __restrict__ cnt, int* __restrict__ rowStart,
    int* __restrict__ blockSums, float* __restrict__ dinv, int N)
{
    __shared__ int tmp[256];
    int t = threadIdx.x;
    int i = blockIdx.x * 256 + t;
    if (i < N) dinv[i] = rsqrtf(dinv[i] + 1.0f);   // deg -> dinv in-place
    int v = (i < N) ? cnt[i] : 0;
    tmp[t] = v;
    __syncthreads();
#pragma unroll
    for (int off = 1; off < 256; off <<= 1) {
        int a = (t >= off) ? tmp[t - off] : 0;
        __syncthreads();
        tmp[t] += a;
        __syncthreads();
    }
    if (i < N) rowStart[i] = tmp[t] - v;
    if (t == 255) blockSums[blockIdx.x] = tmp[255];
}

__global__ __launch_bounds__(512) void scan2_kernel(int* __restrict__ blockSums, int NB)
{
    __shared__ int tmp[512];
    int t = threadIdx.x;
    int v = (t < NB) ? blockSums[t] : 0;
    tmp[t] = v;
    __syncthreads();
#pragma unroll
    for (int off = 1; off < 512; off <<= 1) {
        int a = (t >= off) ? tmp[t - off] : 0;
        __syncthreads();
        tmp[t] += a;
        __syncthreads();
    }
    if (t < NB) blockSums[t] = tmp[t] - v;
}

__global__ __launch_bounds__(256) void scan3_kernel(
    int* __restrict__ rowStart, int* __restrict__ cursor,
    const int* __restrict__ blockSums, int N, int E)
{
    int i = blockIdx.x * 256 + threadIdx.x;
    if (i < N) {
        int r = rowStart[i] + blockSums[blockIdx.x];
        rowStart[i] = r;
        cursor[i]   = r;          // fill's absolute write cursor
    }
    if (i == 0) rowStart[N] = E;
}

// ---- fill CSR (interleaved {src, w}) --------------------------------------

__global__ __launch_bounds__(256) void fill_kernel(
    const int* __restrict__ src, const int* __restrict__ dst,
    const float* __restrict__ ew, const float* __restrict__ dinv,
    int* __restrict__ cursor, uint2* __restrict__ csr, int E)
{
    int e = blockIdx.x * 256 + threadIdx.x;
    if (e >= E) return;
    int s = src[e], d = dst[e];
    int pos = atomicAdd(&cursor[d], 1);
    float w = dinv[s] * ew[e] * dinv[d];
    csr[pos] = make_uint2((unsigned)s, __float_as_uint(w));
}

// ---- GEMM: Hb(bf16 packed) = X @ W  (X: M x 128 fp32) ---------------------

template <int NCOL>
__global__ __launch_bounds__(256) void gemm_kernel(
    const float* __restrict__ X, const float* __restrict__ W,
    unsigned* __restrict__ Hb, int M)      // Hb row = NCOL/2 dwords
{
    constexpr int K    = 128;
    constexpr int KT   = 32;
    constexpr int ROWS = 64;
    constexpr int GX   = NCOL / 2;
    constexpr int NG   = 256 / GX;
    constexpr int RPT  = ROWS / NG;

    __shared__ float sX[ROWS][KT + 4];
    __shared__ float sW[KT][NCOL];

    const int tid   = threadIdx.x;
    const int tx    = tid % GX;
    const int tg    = tid / GX;
    const int rbase = blockIdx.x * ROWS;

    float acc[RPT][2];
#pragma unroll
    for (int r = 0; r < RPT; ++r) { acc[r][0] = 0.f; acc[r][1] = 0.f; }

    for (int kb = 0; kb < K; kb += KT) {
#pragma unroll
        for (int it = 0; it < (ROWS * KT / 4) / 256; ++it) {
            int fq  = tid + it * 256;
            int row = fq / (KT / 4);
            int kc  = fq % (KT / 4);
            int gr  = rbase + row;
            float4 v = make_float4(0.f, 0.f, 0.f, 0.f);
            if (gr < M) v = *(const float4*)&X[(size_t)gr * K + kb + kc * 4];
            *(float4*)&sX[row][kc * 4] = v;
        }
#pragma unroll
        for (int it = 0; it < (KT * NCOL / 4) / 256; ++it) {
            int fq = tid + it * 256;
            int k  = fq / (NCOL / 4);
            int c  = fq % (NCOL / 4);
            *(float4*)&sW[k][c * 4] = *(const float4*)&W[(size_t)(kb + k) * NCOL + c * 4];
        }
        __syncthreads();

#pragma unroll
        for (int kc = 0; kc < KT; kc += 4) {
            float2 w0 = *(float2*)&sW[kc + 0][2 * tx];
            float2 w1 = *(float2*)&sW[kc + 1][2 * tx];
            float2 w2 = *(float2*)&sW[kc + 2][2 * tx];
            float2 w3 = *(float2*)&sW[kc + 3][2 * tx];
#pragma unroll
            for (int r = 0; r < RPT; ++r) {
                float4 xv = *(float4*)&sX[tg * RPT + r][kc];
                acc[r][0] = fmaf(xv.x, w0.x, acc[r][0]);
                acc[r][1] = fmaf(xv.x, w0.y, acc[r][1]);
                acc[r][0] = fmaf(xv.y, w1.x, acc[r][0]);
                acc[r][1] = fmaf(xv.y, w1.y, acc[r][1]);
                acc[r][0] = fmaf(xv.z, w2.x, acc[r][0]);
                acc[r][1] = fmaf(xv.z, w2.y, acc[r][1]);
                acc[r][0] = fmaf(xv.w, w3.x, acc[r][0]);
                acc[r][1] = fmaf(xv.w, w3.y, acc[r][1]);
            }
        }
        __syncthreads();
    }

#pragma unroll
    for (int r = 0; r < RPT; ++r) {
        int gr = rbase + tg * RPT + r;
        if (gr < M) {
            unsigned pack = bf16r(acc[r][0]) | (bf16r(acc[r][1]) << 16);
            Hb[(size_t)gr * GX + tx] = pack;
        }
    }
}

// ---- gather C=128: one wave per node, lane owns channels {2l, 2l+1} -------

template <bool RELU>
__global__ __launch_bounds__(256) void gather128_kernel(
    const int* __restrict__ rowStart, const uint2* __restrict__ csr,
    const unsigned* __restrict__ Hb,               // row = 64 dwords
    const float* __restrict__ dinv, const float* __restrict__ bias,
    float* __restrict__ OUT, int N)
{
    int node = blockIdx.x * 4 + (threadIdx.x >> 6);
    if (node >= N) return;
    int lane = threadIdx.x & 63;

    float di = dinv[node];
    float d2 = di * di;
    unsigned su = Hb[(size_t)node * 64 + lane];
    float a0 = bf_lo(su) * d2;
    float a1 = bf_hi(su) * d2;

    int beg = rowStart[node], end = rowStart[node + 1];
    for (int j = beg; j < end; j += 64) {
        int m = end - j;
        if (m > 64) m = 64;
        int cs = 0, cw = 0;
        if (lane < m) {
            uint2 p = csr[j + lane];
            cs = (int)p.x; cw = (int)p.y;
        }
        int k = 0;
        for (; k + 4 <= m; k += 4) {
            int s0 = __shfl(cs, k + 0); float w0 = __uint_as_float(__shfl(cw, k + 0));
            int s1 = __shfl(cs, k + 1); float w1 = __uint_as_float(__shfl(cw, k + 1));
            int s2 = __shfl(cs, k + 2); float w2 = __uint_as_float(__shfl(cw, k + 2));
            int s3 = __shfl(cs, k + 3); float w3 = __uint_as_float(__shfl(cw, k + 3));
            unsigned u0 = Hb[(size_t)s0 * 64 + lane];
            unsigned u1 = Hb[(size_t)s1 * 64 + lane];
            unsigned u2 = Hb[(size_t)s2 * 64 + lane];
            unsigned u3 = Hb[(size_t)s3 * 64 + lane];
            a0 = fmaf(bf_lo(u0), w0, a0); a1 = fmaf(bf_hi(u0), w0, a1);
            a0 = fmaf(bf_lo(u1), w1, a0); a1 = fmaf(bf_hi(u1), w1, a1);
            a0 = fmaf(bf_lo(u2), w2, a0); a1 = fmaf(bf_hi(u2), w2, a1);
            a0 = fmaf(bf_lo(u3), w3, a0); a1 = fmaf(bf_hi(u3), w3, a1);
        }
        for (; k < m; ++k) {
            int s = __shfl(cs, k); float w = __uint_as_float(__shfl(cw, k));
            unsigned u = Hb[(size_t)s * 64 + lane];
            a0 = fmaf(bf_lo(u), w, a0); a1 = fmaf(bf_hi(u), w, a1);
        }
    }

    int c = lane * 2;
    float o0 = a0 + bias[c];
    float o1 = a1 + bias[c + 1];
    if (RELU) { o0 = fmaxf(o0, 0.f); o1 = fmaxf(o1, 0.f); }
    *(float2*)&OUT[(size_t)node * 128 + c] = make_float2(o0, o1);
}

// ---- gather C=64: 32-lane sub-wave per node -------------------------------

template <bool RELU>
__global__ __launch_bounds__(256) void gather64_kernel(
    const int* __restrict__ rowStart, const uint2* __restrict__ csr,
    const unsigned* __restrict__ Hb,               // row = 32 dwords
    const float* __restrict__ dinv, const float* __restrict__ bias,
    float* __restrict__ OUT, int N)
{
    int node = blockIdx.x * 8 + (threadIdx.x >> 5);
    if (node >= N) return;
    int lane = threadIdx.x & 31;

    float di = dinv[node];
    float d2 = di * di;
    unsigned su = Hb[(size_t)node * 32 + lane];
    float a0 = bf_lo(su) * d2;
    float a1 = bf_hi(su) * d2;

    int beg = rowStart[node], end = rowStart[node + 1];
    for (int j = beg; j < end; j += 32) {
        int m = end - j;
        if (m > 32) m = 32;
        int cs = 0, cw = 0;
        if (lane < m) {
            uint2 p = csr[j + lane];
            cs = (int)p.x; cw = (int)p.y;
        }
        int k = 0;
        for (; k + 4 <= m; k += 4) {
            int s0 = __shfl(cs, k + 0, 32); float w0 = __uint_as_float(__shfl(cw, k + 0, 32));
            int s1 = __shfl(cs, k + 1, 32); float w1 = __uint_as_float(__shfl(cw, k + 1, 32));
            int s2 = __shfl(cs, k + 2, 32); float w2 = __uint_as_float(__shfl(cw, k + 2, 32));
            int s3 = __shfl(cs, k + 3, 32); float w3 = __uint_as_float(__shfl(cw, k + 3, 32));
            unsigned u0 = Hb[(size_t)s0 * 32 + lane];
            unsigned u1 = Hb[(size_t)s1 * 32 + lane];
            unsigned u2 = Hb[(size_t)s2 * 32 + lane];
            unsigned u3 = Hb[(size_t)s3 * 32 + lane];
            a0 = fmaf(bf_lo(u0), w0, a0); a1 = fmaf(bf_hi(u0), w0, a1);
            a0 = fmaf(bf_lo(u1), w1, a0); a1 = fmaf(bf_hi(u1), w1, a1);
            a0 = fmaf(bf_lo(u2), w2, a0); a1 = fmaf(bf_hi(u2), w2, a1);
            a0 = fmaf(bf_lo(u3), w3, a0); a1 = fmaf(bf_hi(u3), w3, a1);
        }
        for (; k < m; ++k) {
            int s = __shfl(cs, k, 32); float w = __uint_as_float(__shfl(cw, k, 32));
            unsigned u = Hb[(size_t)s * 32 + lane];
            a0 = fmaf(bf_lo(u), w, a0); a1 = fmaf(bf_hi(u), w, a1);
        }
    }

    int c = lane * 2;
    float o0 = a0 + bias[c];
    float o1 = a1 + bias[c + 1];
    if (RELU) { o0 = fmaxf(o0, 0.f); o1 = fmaxf(o1, 0.f); }
    *(float2*)&OUT[(size_t)node * 64 + c] = make_float2(o0, o1);
}

static inline size_t align_up(size_t x) { return (x + 255) & ~size_t(255); }

extern "C" void kernel_launch(void* const* d_in, const int* in_sizes, int n_in,
                              void* d_out, int out_size, void* d_ws, size_t ws_size,
                              hipStream_t stream)
{
    const float* x  = (const float*)d_in[0];
    const int*   ei = (const int*)d_in[1];
    const float* ew = (const float*)d_in[2];
    const float* W1 = (const float*)d_in[3];
    const float* b1 = (const float*)d_in[4];
    const float* W2 = (const float*)d_in[5];
    const float* b2 = (const float*)d_in[6];
    float* out = (float*)d_out;

    const int N = N_NODES;
    const int E = in_sizes[2];
    const int* src = ei;
    const int* dst = ei + E;

    const int NB = (N + 255) / 256;
    const int EB = (E + 255) / 256;

    char* ws = (char*)d_ws;
    float* dinv     = (float*)ws; ws += align_up((size_t)N * 4);
    int*   cnt      = (int*)ws;   ws += align_up((size_t)N * 4);       // adjacent to dinv
    int*   rowStart = (int*)ws;   ws += align_up(((size_t)N + 1) * 4);
    int*   cursor   = (int*)ws;   ws += align_up((size_t)N * 4);
    int*   blockSums= (int*)ws;   ws += align_up((size_t)NB * 4);
    uint2* csr      = (uint2*)ws; ws += align_up((size_t)E * 8);
    unsigned* h1    = (unsigned*)ws; ws += align_up((size_t)N * 128 * 2); // bf16 packed
    float*    g1    = (float*)ws;    ws += align_up((size_t)N * 128 * 4);
    unsigned* h2    = (unsigned*)ws; ws += align_up((size_t)N * 64 * 2);  // bf16 packed

    // zero deg + cnt in one shot (adjacent)
    hipMemsetAsync(dinv, 0, align_up((size_t)N * 4) + (size_t)N * 4, stream);
    deg_count_kernel<<<EB, 256, 0, stream>>>(dst, ew, dinv, cnt, E);
    scan1_kernel<<<NB, 256, 0, stream>>>(cnt, rowStart, blockSums, dinv, N);
    scan2_kernel<<<1, 512, 0, stream>>>(blockSums, NB);
    scan3_kernel<<<NB, 256, 0, stream>>>(rowStart, cursor, blockSums, N, E);
    fill_kernel<<<EB, 256, 0, stream>>>(src, dst, ew, dinv, cursor, csr, E);

    // ---- layer 1 ----
    gemm_kernel<128><<<(N + 63) / 64, 256, 0, stream>>>(x, W1, h1, N);
    gather128_kernel<true><<<(N + 3) / 4, 256, 0, stream>>>(
        rowStart, csr, h1, dinv, b1, g1, N);

    // ---- layer 2 ----
    gemm_kernel<64><<<(N + 63) / 64, 256, 0, stream>>>(g1, W2, h2, N);
    gather64_kernel<false><<<(N + 7) / 8, 256, 0, stream>>>(
        rowStart, csr, h2, dinv, b2, out, N);
}

// Round 5
// 446.153 us; speedup vs baseline: 9.7659x; 1.1566x over previous
//
#include <hip/hip_runtime.h>

// ---------------------------------------------------------------------------
// Two-layer GCN on MI355X.  Round 5 (= Round 4 + self-loop fix):
//   - deg+count in ONE packed 64-bit atomic per edge (cnt<<32 | ew*2^24)
//   - gather: wave per node, lanes = edge-slots x channel-groups, uint4
//     (16 B) row loads -> 4-8 edges in flight, shfl_xor cross-slot reduce
//   - self-loop init ONLY in slot-0 lanes (was counted q-times -> R4 fail)
//   - h stored bf16-packed
// ---------------------------------------------------------------------------

#define N_NODES 100000

__device__ __forceinline__ unsigned bf16r(float f) {
    unsigned u = __float_as_uint(f);
    return (u + 0x7fffu + ((u >> 16) & 1u)) >> 16;     // RNE
}
__device__ __forceinline__ float bf_lo(unsigned u) { return __uint_as_float(u << 16); }
__device__ __forceinline__ float bf_hi(unsigned u) { return __uint_as_float(u & 0xffff0000u); }

// ---- packed degree+count: one u64 atomic per edge -------------------------

__global__ __launch_bounds__(256) void deg_count_kernel(
    const int* __restrict__ dst, const float* __restrict__ ew,
    unsigned long long* __restrict__ degcnt, int E)
{
    int e = blockIdx.x * 256 + threadIdx.x;
    if (e < E) {
        unsigned fx = (unsigned)__float2uint_rn(ew[e] * 16777216.0f);  // 2^24
        atomicAdd(&degcnt[dst[e]], (1ull << 32) | (unsigned long long)fx);
    }
}

// ---- scan1: unpack degcnt -> dinv + block-local exclusive scan of counts --

__global__ __launch_bounds__(256) void scan1_kernel(
    const unsigned long long* __restrict__ degcnt, int* __restrict__ rowStart,
    int* __restrict__ blockSums, float* __restrict__ dinv, int N)
{
    __shared__ int tmp[256];
    int t = threadIdx.x;
    int i = blockIdx.x * 256 + t;
    int v = 0;
    if (i < N) {
        unsigned long long dc = degcnt[i];
        float deg = (float)(unsigned)(dc & 0xffffffffull) * (1.0f / 16777216.0f);
        dinv[i] = rsqrtf(deg + 1.0f);
        v = (int)(dc >> 32);
    }
    tmp[t] = v;
    __syncthreads();
#pragma unroll
    for (int off = 1; off < 256; off <<= 1) {
        int a = (t >= off) ? tmp[t - off] : 0;
        __syncthreads();
        tmp[t] += a;
        __syncthreads();
    }
    if (i < N) rowStart[i] = tmp[t] - v;
    if (t == 255) blockSums[blockIdx.x] = tmp[255];
}

__global__ __launch_bounds__(512) void scan2_kernel(int* __restrict__ blockSums, int NB)
{
    __shared__ int tmp[512];
    int t = threadIdx.x;
    int v = (t < NB) ? blockSums[t] : 0;
    tmp[t] = v;
    __syncthreads();
#pragma unroll
    for (int off = 1; off < 512; off <<= 1) {
        int a = (t >= off) ? tmp[t - off] : 0;
        __syncthreads();
        tmp[t] += a;
        __syncthreads();
    }
    if (t < NB) blockSums[t] = tmp[t] - v;
}

__global__ __launch_bounds__(256) void scan3_kernel(
    int* __restrict__ rowStart, int* __restrict__ cursor,
    const int* __restrict__ blockSums, int N, int E)
{
    int i = blockIdx.x * 256 + threadIdx.x;
    if (i < N) {
        int r = rowStart[i] + blockSums[blockIdx.x];
        rowStart[i] = r;
        cursor[i]   = r;
    }
    if (i == 0) rowStart[N] = E;
}

// ---- fill CSR (interleaved {src, w}) --------------------------------------

__global__ __launch_bounds__(256) void fill_kernel(
    const int* __restrict__ src, const int* __restrict__ dst,
    const float* __restrict__ ew, const float* __restrict__ dinv,
    int* __restrict__ cursor, uint2* __restrict__ csr, int E)
{
    int e = blockIdx.x * 256 + threadIdx.x;
    if (e >= E) return;
    int s = src[e], d = dst[e];
    int pos = atomicAdd(&cursor[d], 1);
    float w = dinv[s] * ew[e] * dinv[d];
    csr[pos] = make_uint2((unsigned)s, __float_as_uint(w));
}

// ---- GEMM: Hb(bf16 packed) = X @ W  (X: M x 128 fp32) ---------------------

template <int NCOL>
__global__ __launch_bounds__(256) void gemm_kernel(
    const float* __restrict__ X, const float* __restrict__ W,
    unsigned* __restrict__ Hb, int M)      // Hb row = NCOL/2 dwords
{
    constexpr int K    = 128;
    constexpr int KT   = 32;
    constexpr int ROWS = 64;
    constexpr int GX   = NCOL / 2;
    constexpr int NG   = 256 / GX;
    constexpr int RPT  = ROWS / NG;

    __shared__ float sX[ROWS][KT + 4];
    __shared__ float sW[KT][NCOL];

    const int tid   = threadIdx.x;
    const int tx    = tid % GX;
    const int tg    = tid / GX;
    const int rbase = blockIdx.x * ROWS;

    float acc[RPT][2];
#pragma unroll
    for (int r = 0; r < RPT; ++r) { acc[r][0] = 0.f; acc[r][1] = 0.f; }

    for (int kb = 0; kb < K; kb += KT) {
#pragma unroll
        for (int it = 0; it < (ROWS * KT / 4) / 256; ++it) {
            int fq  = tid + it * 256;
            int row = fq / (KT / 4);
            int kc  = fq % (KT / 4);
            int gr  = rbase + row;
            float4 v = make_float4(0.f, 0.f, 0.f, 0.f);
            if (gr < M) v = *(const float4*)&X[(size_t)gr * K + kb + kc * 4];
            *(float4*)&sX[row][kc * 4] = v;
        }
#pragma unroll
        for (int it = 0; it < (KT * NCOL / 4) / 256; ++it) {
            int fq = tid + it * 256;
            int k  = fq / (NCOL / 4);
            int c  = fq % (NCOL / 4);
            *(float4*)&sW[k][c * 4] = *(const float4*)&W[(size_t)(kb + k) * NCOL + c * 4];
        }
        __syncthreads();

#pragma unroll
        for (int kc = 0; kc < KT; kc += 4) {
            float2 w0 = *(float2*)&sW[kc + 0][2 * tx];
            float2 w1 = *(float2*)&sW[kc + 1][2 * tx];
            float2 w2 = *(float2*)&sW[kc + 2][2 * tx];
            float2 w3 = *(float2*)&sW[kc + 3][2 * tx];
#pragma unroll
            for (int r = 0; r < RPT; ++r) {
                float4 xv = *(float4*)&sX[tg * RPT + r][kc];
                acc[r][0] = fmaf(xv.x, w0.x, acc[r][0]);
                acc[r][1] = fmaf(xv.x, w0.y, acc[r][1]);
                acc[r][0] = fmaf(xv.y, w1.x, acc[r][0]);
                acc[r][1] = fmaf(xv.y, w1.y, acc[r][1]);
                acc[r][0] = fmaf(xv.z, w2.x, acc[r][0]);
                acc[r][1] = fmaf(xv.z, w2.y, acc[r][1]);
                acc[r][0] = fmaf(xv.w, w3.x, acc[r][0]);
                acc[r][1] = fmaf(xv.w, w3.y, acc[r][1]);
            }
        }
        __syncthreads();
    }

#pragma unroll
    for (int r = 0; r < RPT; ++r) {
        int gr = rbase + tg * RPT + r;
        if (gr < M) {
            unsigned pack = bf16r(acc[r][0]) | (bf16r(acc[r][1]) << 16);
            Hb[(size_t)gr * GX + tx] = pack;
        }
    }
}

// ---- gather C=128: wave per node; lane = (q=edge-slot 0..3, cg=chan-grp 0..15)
// lane loads 16 B (8 bf16 channels) of its slot's source row -> 4 edges/iter.

template <bool RELU>
__global__ __launch_bounds__(256) void gather128_kernel(
    const int* __restrict__ rowStart, const uint2* __restrict__ csr,
    const uint4* __restrict__ Hb4,                 // row = 16 uint4
    const float* __restrict__ dinv, const float* __restrict__ bias,
    float* __restrict__ OUT, int N)
{
    int node = blockIdx.x * 4 + (threadIdx.x >> 6);
    if (node >= N) return;
    int lane = threadIdx.x & 63;
    int q  = lane >> 4;        // edge slot 0..3
    int cg = lane & 15;        // channel group: channels cg*8 .. cg*8+7

    // self-loop ONLY in slot-0 lanes (acc is summed across slots at the end)
    float d2; { float di = dinv[node]; d2 = (q == 0) ? di * di : 0.f; }
    float acc[8];
    {
        uint4 su = Hb4[(size_t)node * 16 + cg];
        acc[0] = bf_lo(su.x) * d2; acc[1] = bf_hi(su.x) * d2;
        acc[2] = bf_lo(su.y) * d2; acc[3] = bf_hi(su.y) * d2;
        acc[4] = bf_lo(su.z) * d2; acc[5] = bf_hi(su.z) * d2;
        acc[6] = bf_lo(su.w) * d2; acc[7] = bf_hi(su.w) * d2;
    }

    int beg = rowStart[node], end = rowStart[node + 1];
    for (int j = beg; j < end; j += 64) {
        int cs = 0, cw = 0;
        if (j + lane < end) {
            uint2 p = csr[j + lane];
            cs = (int)p.x; cw = (int)p.y;
        }
        int mm = end - j; if (mm > 64) mm = 64;
#pragma unroll 4
        for (int k = 0; k < mm; k += 4) {
            int   idx = k + q;
            int   s = __shfl(cs, idx);
            float w = __uint_as_float(__shfl(cw, idx));   // 0 for idx >= mm
            uint4 u = Hb4[(size_t)s * 16 + cg];
            acc[0] = fmaf(bf_lo(u.x), w, acc[0]); acc[1] = fmaf(bf_hi(u.x), w, acc[1]);
            acc[2] = fmaf(bf_lo(u.y), w, acc[2]); acc[3] = fmaf(bf_hi(u.y), w, acc[3]);
            acc[4] = fmaf(bf_lo(u.z), w, acc[4]); acc[5] = fmaf(bf_hi(u.z), w, acc[5]);
            acc[6] = fmaf(bf_lo(u.w), w, acc[6]); acc[7] = fmaf(bf_hi(u.w), w, acc[7]);
        }
    }

    // sum the 4 edge-slots (lanes differing in bits 4,5)
#pragma unroll
    for (int v = 0; v < 8; ++v) {
        acc[v] += __shfl_xor(acc[v], 16);
        acc[v] += __shfl_xor(acc[v], 32);
    }

    // lane writes channels cg*8 + 2q, +2q+1
    int c = cg * 8 + q * 2;
    float o0 = acc[q * 2]     + bias[c];
    float o1 = acc[q * 2 + 1] + bias[c + 1];
    if (RELU) { o0 = fmaxf(o0, 0.f); o1 = fmaxf(o1, 0.f); }
    *(float2*)&OUT[(size_t)node * 128 + c] = make_float2(o0, o1);
}

// ---- gather C=64: wave per node; q=slot 0..7, cg=chan-grp 0..7 ------------

template <bool RELU>
__global__ __launch_bounds__(256) void gather64_kernel(
    const int* __restrict__ rowStart, const uint2* __restrict__ csr,
    const uint4* __restrict__ Hb4,                 // row = 8 uint4
    const float* __restrict__ dinv, const float* __restrict__ bias,
    float* __restrict__ OUT, int N)
{
    int node = blockIdx.x * 4 + (threadIdx.x >> 6);
    if (node >= N) return;
    int lane = threadIdx.x & 63;
    int q  = lane >> 3;        // edge slot 0..7
    int cg = lane & 7;         // channels cg*8 .. cg*8+7

    // self-loop ONLY in slot-0 lanes
    float d2; { float di = dinv[node]; d2 = (q == 0) ? di * di : 0.f; }
    float acc[8];
    {
        uint4 su = Hb4[(size_t)node * 8 + cg];
        acc[0] = bf_lo(su.x) * d2; acc[1] = bf_hi(su.x) * d2;
        acc[2] = bf_lo(su.y) * d2; acc[3] = bf_hi(su.y) * d2;
        acc[4] = bf_lo(su.z) * d2; acc[5] = bf_hi(su.z) * d2;
        acc[6] = bf_lo(su.w) * d2; acc[7] = bf_hi(su.w) * d2;
    }

    int beg = rowStart[node], end = rowStart[node + 1];
    for (int j = beg; j < end; j += 64) {
        int cs = 0, cw = 0;
        if (j + lane < end) {
            uint2 p = csr[j + lane];
            cs = (int)p.x; cw = (int)p.y;
        }
        int mm = end - j; if (mm > 64) mm = 64;
#pragma unroll 2
        for (int k = 0; k < mm; k += 8) {
            int   idx = k + q;
            int   s = __shfl(cs, idx);
            float w = __uint_as_float(__shfl(cw, idx));
            uint4 u = Hb4[(size_t)s * 8 + cg];
            acc[0] = fmaf(bf_lo(u.x), w, acc[0]); acc[1] = fmaf(bf_hi(u.x), w, acc[1]);
            acc[2] = fmaf(bf_lo(u.y), w, acc[2]); acc[3] = fmaf(bf_hi(u.y), w, acc[3]);
            acc[4] = fmaf(bf_lo(u.z), w, acc[4]); acc[5] = fmaf(bf_hi(u.z), w, acc[5]);
            acc[6] = fmaf(bf_lo(u.w), w, acc[6]); acc[7] = fmaf(bf_hi(u.w), w, acc[7]);
        }
    }

    // sum the 8 edge-slots (lanes differing in bits 3,4,5)
#pragma unroll
    for (int v = 0; v < 8; ++v) {
        acc[v] += __shfl_xor(acc[v], 8);
        acc[v] += __shfl_xor(acc[v], 16);
        acc[v] += __shfl_xor(acc[v], 32);
    }

    // lane writes channel cg*8 + q
    int c = cg * 8 + q;
    float o = acc[q] + bias[c];
    if (RELU) o = fmaxf(o, 0.f);
    OUT[(size_t)node * 64 + c] = o;
}

static inline size_t align_up(size_t x) { return (x + 255) & ~size_t(255); }

extern "C" void kernel_launch(void* const* d_in, const int* in_sizes, int n_in,
                              void* d_out, int out_size, void* d_ws, size_t ws_size,
                              hipStream_t stream)
{
    const float* x  = (const float*)d_in[0];
    const int*   ei = (const int*)d_in[1];
    const float* ew = (const float*)d_in[2];
    const float* W1 = (const float*)d_in[3];
    const float* b1 = (const float*)d_in[4];
    const float* W2 = (const float*)d_in[5];
    const float* b2 = (const float*)d_in[6];
    float* out = (float*)d_out;

    const int N = N_NODES;
    const int E = in_sizes[2];
    const int* src = ei;
    const int* dst = ei + E;

    const int NB = (N + 255) / 256;
    const int EB = (E + 255) / 256;

    char* ws = (char*)d_ws;
    unsigned long long* degcnt = (unsigned long long*)ws; ws += align_up((size_t)N * 8);
    float* dinv     = (float*)ws; ws += align_up((size_t)N * 4);
    int*   rowStart = (int*)ws;   ws += align_up(((size_t)N + 1) * 4);
    int*   cursor   = (int*)ws;   ws += align_up((size_t)N * 4);
    int*   blockSums= (int*)ws;   ws += align_up((size_t)NB * 4);
    uint2* csr      = (uint2*)ws; ws += align_up((size_t)E * 8);
    unsigned* h1    = (unsigned*)ws; ws += align_up((size_t)N * 128 * 2); // bf16 packed
    float*    g1    = (float*)ws;    ws += align_up((size_t)N * 128 * 4);
    unsigned* h2    = (unsigned*)ws; ws += align_up((size_t)N * 64 * 2);  // bf16 packed

    hipMemsetAsync(degcnt, 0, (size_t)N * 8, stream);
    deg_count_kernel<<<EB, 256, 0, stream>>>(dst, ew, degcnt, E);
    scan1_kernel<<<NB, 256, 0, stream>>>(degcnt, rowStart, blockSums, dinv, N);
    scan2_kernel<<<1, 512, 0, stream>>>(blockSums, NB);
    scan3_kernel<<<NB, 256, 0, stream>>>(rowStart, cursor, blockSums, N, E);
    fill_kernel<<<EB, 256, 0, stream>>>(src, dst, ew, dinv, cursor, csr, E);

    // ---- layer 1 ----
    gemm_kernel<128><<<(N + 63) / 64, 256, 0, stream>>>(x, W1, h1, N);
    gather128_kernel<true><<<(N + 3) / 4, 256, 0, stream>>>(
        rowStart, csr, (const uint4*)h1, dinv, b1, g1, N);

    // ---- layer 2 ----
    gemm_kernel<64><<<(N + 63) / 64, 256, 0, stream>>>(g1, W2, h2, N);
    gather64_kernel<false><<<(N + 3) / 4, 256, 0, stream>>>(
        rowStart, csr, (const uint4*)h2, dinv, b2, out, N);
}

// Round 6
// 339.900 us; speedup vs baseline: 12.8187x; 1.3126x over previous
//
#include <hip/hip_runtime.h>

// ---------------------------------------------------------------------------
// Two-layer GCN on MI355X.  Round 6: deterministic two-level counting sort
// for the CSR build (kills the 8x random-line write amplification that made
// deg_count/fill ~155us):
//   A1    : per-block LDS histogram over 196 dst-buckets -> histmat
//   scanB : per-bucket scan over blocks -> deterministic bases + sizes
//   A2    : LDS reorder, bucket-grouped contiguous writes to csrTmp
//   B1    : per-bucket LDS degree+count (u64), rsqrt, local scan -> dinv,
//           nodeinfo{begin,cnt}   (replaces deg_count + scan1/2/3)
//   B2    : per-bucket local sort + w=dinv[s]*ew*dinv[d] -> csrFinal
// Gather (reg-accumulating, uint4 bf16 rows) + fp32 GEMM unchanged from R5.
// ---------------------------------------------------------------------------

#define N_NODES 100000
#define CHUNK   2048                 // edges per partition block
#define NBUCK   196                  // ceil(100000/512)
#define BSHIFT  9                    // bucket = dst >> 9, 512 nodes/bucket
#define BNODES  512
#define CAP     10240                // per-bucket capacity (mean 8192 + 22 sigma)

__device__ __forceinline__ unsigned bf16r(float f) {
    unsigned u = __float_as_uint(f);
    return (u + 0x7fffu + ((u >> 16) & 1u)) >> 16;     // RNE
}
__device__ __forceinline__ float bf_lo(unsigned u) { return __uint_as_float(u << 16); }
__device__ __forceinline__ float bf_hi(unsigned u) { return __uint_as_float(u & 0xffff0000u); }

// ---- A1: per-block histogram over buckets ---------------------------------

__global__ __launch_bounds__(256) void partA1_kernel(
    const int* __restrict__ dst, int* __restrict__ histmat, int E)
{
    __shared__ int hist[256];
    int t = threadIdx.x, blk = blockIdx.x;
    hist[t] = 0;
    __syncthreads();
    int e0 = blk * CHUNK;
    int nv = min(CHUNK, E - e0);
#pragma unroll
    for (int j = 0; j < CHUNK / 256; ++j) {
        int idx = t + j * 256;
        if (idx < nv) atomicAdd(&hist[dst[e0 + idx] >> BSHIFT], 1);
    }
    __syncthreads();
    histmat[blk * 256 + t] = hist[t];
}

// ---- scanB: per-bucket exclusive scan over block rows ---------------------
// converts histmat counts -> per-(block,bucket) base; writes bucketSize.

__global__ __launch_bounds__(256) void scanB_kernel(
    int* __restrict__ histmat, int* __restrict__ bucketSize, int NBLK)
{
    __shared__ int sums[256];
    int b = blockIdx.x, t = threadIdx.x;
    const int PER = (NBLK + 255) / 256;      // <= 8 for E <= 4.2M
    int loc[8];
    int s = 0;
#pragma unroll 8
    for (int j = 0; j < PER; ++j) {
        int r = t * PER + j;
        int v = (r < NBLK) ? histmat[r * 256 + b] : 0;
        loc[j] = v; s += v;
    }
    sums[t] = s;
    __syncthreads();
    int v = s;
#pragma unroll
    for (int off = 1; off < 256; off <<= 1) {
        int a = (t >= off) ? sums[t - off] : 0;
        __syncthreads();
        sums[t] += a;
        __syncthreads();
    }
    if (t == 255) bucketSize[b] = sums[255];
    int run = sums[t] - v;                    // exclusive base for this thread's rows
#pragma unroll 8
    for (int j = 0; j < PER; ++j) {
        int r = t * PER + j;
        if (r < NBLK) { histmat[r * 256 + b] = run; run += loc[j]; }
    }
}

// ---- A2: reorder block's edges by bucket, write grouped runs --------------

__global__ __launch_bounds__(256) void partA2_kernel(
    const int* __restrict__ src, const int* __restrict__ dst,
    const float* __restrict__ ew, const int* __restrict__ histmat,
    uint2* __restrict__ csrTmp, int E)
{
    __shared__ int hist[256], sc[256], exc[256], lcur[256], basel[256];
    __shared__ uint2 ent[CHUNK];
    __shared__ unsigned short bof[CHUNK];

    int t = threadIdx.x, blk = blockIdx.x;
    hist[t] = 0; lcur[t] = 0;
    basel[t] = histmat[blk * 256 + t];
    __syncthreads();

    int e0 = blk * CHUNK;
    int nv = min(CHUNK, E - e0);
    int dv[CHUNK / 256]; int sv[CHUNK / 256]; unsigned wv[CHUNK / 256];
#pragma unroll
    for (int j = 0; j < CHUNK / 256; ++j) {
        int idx = t + j * 256;
        if (idx < nv) {
            int e = e0 + idx;
            dv[j] = dst[e]; sv[j] = src[e]; wv[j] = __float_as_uint(ew[e]);
            atomicAdd(&hist[dv[j] >> BSHIFT], 1);
        } else dv[j] = -1;
    }
    __syncthreads();
    // exclusive scan of hist -> exc
    int hv = hist[t];
    sc[t] = hv;
    __syncthreads();
#pragma unroll
    for (int off = 1; off < 256; off <<= 1) {
        int a = (t >= off) ? sc[t - off] : 0;
        __syncthreads();
        sc[t] += a;
        __syncthreads();
    }
    exc[t] = sc[t] - hv;
    __syncthreads();
    // place into LDS grouped by bucket
#pragma unroll
    for (int j = 0; j < CHUNK / 256; ++j) {
        if (dv[j] >= 0) {
            int b  = dv[j] >> BSHIFT;
            int dl = dv[j] & (BNODES - 1);
            int p  = exc[b] + atomicAdd(&lcur[b], 1);
            ent[p] = make_uint2(((unsigned)dl << 17) | (unsigned)sv[j], wv[j]);
            bof[p] = (unsigned short)b;
        }
    }
    __syncthreads();
    // write grouped runs to bucket regions
#pragma unroll
    for (int j = 0; j < CHUNK / 256; ++j) {
        int i = t + j * 256;
        if (i < nv) {
            int b = bof[i];
            size_t addr = (size_t)b * CAP + basel[b] + (i - exc[b]);
            csrTmp[addr] = ent[i];
        }
    }
}

// ---- B1: per-bucket degree/count (LDS), dinv, nodeinfo --------------------

__global__ __launch_bounds__(1024) void bucketB1_kernel(
    const uint2* __restrict__ csrTmp, const int* __restrict__ bucketSize,
    float* __restrict__ dinv, uint2* __restrict__ nodeinfo, int N)
{
    __shared__ unsigned long long dc[BNODES];
    __shared__ int scn[BNODES];
    int b = blockIdx.x, t = threadIdx.x;
    if (t < BNODES) dc[t] = 0ull;
    __syncthreads();

    int sz = bucketSize[b];
    const uint2* reg = csrTmp + (size_t)b * CAP;
    for (int i = t; i < sz; i += 1024) {
        uint2 en = reg[i];
        int dl = (int)(en.x >> 17);
        unsigned fx = (unsigned)__float2uint_rn(__uint_as_float(en.y) * 16777216.0f);
        atomicAdd(&dc[dl], (1ull << 32) | (unsigned long long)fx);
    }
    __syncthreads();

    int cnt = 0; float dv = 1.0f;
    if (t < BNODES) {
        unsigned long long v = dc[t];
        cnt = (int)(v >> 32);
        float deg = (float)(unsigned)(v & 0xffffffffull) * (1.0f / 16777216.0f);
        dv = rsqrtf(deg + 1.0f);
        scn[t] = cnt;
    }
    __syncthreads();
#pragma unroll
    for (int off = 1; off < BNODES; off <<= 1) {
        int a = 0;
        if (t < BNODES && t >= off) a = scn[t - off];
        __syncthreads();
        if (t < BNODES) scn[t] += a;
        __syncthreads();
    }
    if (t < BNODES) {
        int excl = scn[t] - cnt;
        int gn = b * BNODES + t;
        if (gn < N) {
            dinv[gn] = dv;
            nodeinfo[gn] = make_uint2((unsigned)(b * CAP + excl), (unsigned)cnt);
        }
    }
}

// ---- B2: per-bucket local sort + fused norm weight ------------------------

__global__ __launch_bounds__(1024) void bucketB2_kernel(
    const uint2* __restrict__ csrTmp, const int* __restrict__ bucketSize,
    const uint2* __restrict__ nodeinfo, const float* __restrict__ dinv,
    uint2* __restrict__ csrF, int N)
{
    __shared__ float dinv_l[BNODES];
    __shared__ int beg[BNODES], cur[BNODES];
    int b = blockIdx.x, t = threadIdx.x;
    if (t < BNODES) {
        int gn = b * BNODES + t;
        float dv = 1.0f; int bg = 0;
        if (gn < N) { uint2 inf = nodeinfo[gn]; bg = (int)inf.x; dv = dinv[gn]; }
        dinv_l[t] = dv; beg[t] = bg; cur[t] = 0;
    }
    __syncthreads();

    int sz = bucketSize[b];
    const uint2* reg = csrTmp + (size_t)b * CAP;
    for (int i = t; i < sz; i += 1024) {
        uint2 en = reg[i];
        int dl = (int)(en.x >> 17);
        int s  = (int)(en.x & 0x1FFFFu);
        int p  = beg[dl] + atomicAdd(&cur[dl], 1);
        float w = dinv[s] * __uint_as_float(en.y) * dinv_l[dl];
        csrF[p] = make_uint2((unsigned)s, __float_as_uint(w));
    }
}

// ---- GEMM: Hb(bf16 packed) = X @ W  (X: M x 128 fp32) ---------------------

template <int NCOL>
__global__ __launch_bounds__(256) void gemm_kernel(
    const float* __restrict__ X, const float* __restrict__ W,
    unsigned* __restrict__ Hb, int M)      // Hb row = NCOL/2 dwords
{
    constexpr int K    = 128;
    constexpr int KT   = 32;
    constexpr int ROWS = 64;
    constexpr int GX   = NCOL / 2;
    constexpr int NG   = 256 / GX;
    constexpr int RPT  = ROWS / NG;

    __shared__ float sX[ROWS][KT + 4];
    __shared__ float sW[KT][NCOL];

    const int tid   = threadIdx.x;
    const int tx    = tid % GX;
    const int tg    = tid / GX;
    const int rbase = blockIdx.x * ROWS;

    float acc[RPT][2];
#pragma unroll
    for (int r = 0; r < RPT; ++r) { acc[r][0] = 0.f; acc[r][1] = 0.f; }

    for (int kb = 0; kb < K; kb += KT) {
#pragma unroll
        for (int it = 0; it < (ROWS * KT / 4) / 256; ++it) {
            int fq  = tid + it * 256;
            int row = fq / (KT / 4);
            int kc  = fq % (KT / 4);
            int gr  = rbase + row;
            float4 v = make_float4(0.f, 0.f, 0.f, 0.f);
            if (gr < M) v = *(const float4*)&X[(size_t)gr * K + kb + kc * 4];
            *(float4*)&sX[row][kc * 4] = v;
        }
#pragma unroll
        for (int it = 0; it < (KT * NCOL / 4) / 256; ++it) {
            int fq = tid + it * 256;
            int k  = fq / (NCOL / 4);
            int c  = fq % (NCOL / 4);
            *(float4*)&sW[k][c * 4] = *(const float4*)&W[(size_t)(kb + k) * NCOL + c * 4];
        }
        __syncthreads();

#pragma unroll
        for (int kc = 0; kc < KT; kc += 4) {
            float2 w0 = *(float2*)&sW[kc + 0][2 * tx];
            float2 w1 = *(float2*)&sW[kc + 1][2 * tx];
            float2 w2 = *(float2*)&sW[kc + 2][2 * tx];
            float2 w3 = *(float2*)&sW[kc + 3][2 * tx];
#pragma unroll
            for (int r = 0; r < RPT; ++r) {
                float4 xv = *(float4*)&sX[tg * RPT + r][kc];
                acc[r][0] = fmaf(xv.x, w0.x, acc[r][0]);
                acc[r][1] = fmaf(xv.x, w0.y, acc[r][1]);
                acc[r][0] = fmaf(xv.y, w1.x, acc[r][0]);
                acc[r][1] = fmaf(xv.y, w1.y, acc[r][1]);
                acc[r][0] = fmaf(xv.z, w2.x, acc[r][0]);
                acc[r][1] = fmaf(xv.z, w2.y, acc[r][1]);
                acc[r][0] = fmaf(xv.w, w3.x, acc[r][0]);
                acc[r][1] = fmaf(xv.w, w3.y, acc[r][1]);
            }
        }
        __syncthreads();
    }

#pragma unroll
    for (int r = 0; r < RPT; ++r) {
        int gr = rbase + tg * RPT + r;
        if (gr < M) {
            unsigned pack = bf16r(acc[r][0]) | (bf16r(acc[r][1]) << 16);
            Hb[(size_t)gr * GX + tx] = pack;
        }
    }
}

// ---- gather C=128: wave per node; q=edge-slot 0..3, cg=chan-grp 0..15 -----

template <bool RELU>
__global__ __launch_bounds__(256) void gather128_kernel(
    const uint2* __restrict__ nodeinfo, const uint2* __restrict__ csr,
    const uint4* __restrict__ Hb4,                 // row = 16 uint4
    const float* __restrict__ dinv, const float* __restrict__ bias,
    float* __restrict__ OUT, int N)
{
    int node = blockIdx.x * 4 + (threadIdx.x >> 6);
    if (node >= N) return;
    int lane = threadIdx.x & 63;
    int q  = lane >> 4;
    int cg = lane & 15;

    // self-loop ONLY in slot-0 lanes (acc summed across slots at the end)
    float d2; { float di = dinv[node]; d2 = (q == 0) ? di * di : 0.f; }
    float acc[8];
    {
        uint4 su = Hb4[(size_t)node * 16 + cg];
        acc[0] = bf_lo(su.x) * d2; acc[1] = bf_hi(su.x) * d2;
        acc[2] = bf_lo(su.y) * d2; acc[3] = bf_hi(su.y) * d2;
        acc[4] = bf_lo(su.z) * d2; acc[5] = bf_hi(su.z) * d2;
        acc[6] = bf_lo(su.w) * d2; acc[7] = bf_hi(su.w) * d2;
    }

    uint2 inf = nodeinfo[node];
    int beg = (int)inf.x, end = beg + (int)inf.y;
    for (int j = beg; j < end; j += 64) {
        int cs = 0, cw = 0;
        if (j + lane < end) {
            uint2 p = csr[j + lane];
            cs = (int)p.x; cw = (int)p.y;
        }
        int mm = end - j; if (mm > 64) mm = 64;
#pragma unroll 4
        for (int k = 0; k < mm; k += 4) {
            int   idx = k + q;
            int   s = __shfl(cs, idx);
            float w = __uint_as_float(__shfl(cw, idx));   // 0 for idx >= mm
            uint4 u = Hb4[(size_t)s * 16 + cg];
            acc[0] = fmaf(bf_lo(u.x), w, acc[0]); acc[1] = fmaf(bf_hi(u.x), w, acc[1]);
            acc[2] = fmaf(bf_lo(u.y), w, acc[2]); acc[3] = fmaf(bf_hi(u.y), w, acc[3]);
            acc[4] = fmaf(bf_lo(u.z), w, acc[4]); acc[5] = fmaf(bf_hi(u.z), w, acc[5]);
            acc[6] = fmaf(bf_lo(u.w), w, acc[6]); acc[7] = fmaf(bf_hi(u.w), w, acc[7]);
        }
    }

#pragma unroll
    for (int v = 0; v < 8; ++v) {
        acc[v] += __shfl_xor(acc[v], 16);
        acc[v] += __shfl_xor(acc[v], 32);
    }

    int c = cg * 8 + q * 2;
    float o0 = acc[q * 2]     + bias[c];
    float o1 = acc[q * 2 + 1] + bias[c + 1];
    if (RELU) { o0 = fmaxf(o0, 0.f); o1 = fmaxf(o1, 0.f); }
    *(float2*)&OUT[(size_t)node * 128 + c] = make_float2(o0, o1);
}

// ---- gather C=64: wave per node; q=slot 0..7, cg=chan-grp 0..7 ------------

template <bool RELU>
__global__ __launch_bounds__(256) void gather64_kernel(
    const uint2* __restrict__ nodeinfo, const uint2* __restrict__ csr,
    const uint4* __restrict__ Hb4,                 // row = 8 uint4
    const float* __restrict__ dinv, const float* __restrict__ bias,
    float* __restrict__ OUT, int N)
{
    int node = blockIdx.x * 4 + (threadIdx.x >> 6);
    if (node >= N) return;
    int lane = threadIdx.x & 63;
    int q  = lane >> 3;
    int cg = lane & 7;

    float d2; { float di = dinv[node]; d2 = (q == 0) ? di * di : 0.f; }
    float acc[8];
    {
        uint4 su = Hb4[(size_t)node * 8 + cg];
        acc[0] = bf_lo(su.x) * d2; acc[1] = bf_hi(su.x) * d2;
        acc[2] = bf_lo(su.y) * d2; acc[3] = bf_hi(su.y) * d2;
        acc[4] = bf_lo(su.z) * d2; acc[5] = bf_hi(su.z) * d2;
        acc[6] = bf_lo(su.w) * d2; acc[7] = bf_hi(su.w) * d2;
    }

    uint2 inf = nodeinfo[node];
    int beg = (int)inf.x, end = beg + (int)inf.y;
    for (int j = beg; j < end; j += 64) {
        int cs = 0, cw = 0;
        if (j + lane < end) {
            uint2 p = csr[j + lane];
            cs = (int)p.x; cw = (int)p.y;
        }
        int mm = end - j; if (mm > 64) mm = 64;
#pragma unroll 2
        for (int k = 0; k < mm; k += 8) {
            int   idx = k + q;
            int   s = __shfl(cs, idx);
            float w = __uint_as_float(__shfl(cw, idx));
            uint4 u = Hb4[(size_t)s * 8 + cg];
            acc[0] = fmaf(bf_lo(u.x), w, acc[0]); acc[1] = fmaf(bf_hi(u.x), w, acc[1]);
            acc[2] = fmaf(bf_lo(u.y), w, acc[2]); acc[3] = fmaf(bf_hi(u.y), w, acc[3]);
            acc[4] = fmaf(bf_lo(u.z), w, acc[4]); acc[5] = fmaf(bf_hi(u.z), w, acc[5]);
            acc[6] = fmaf(bf_lo(u.w), w, acc[6]); acc[7] = fmaf(bf_hi(u.w), w, acc[7]);
        }
    }

#pragma unroll
    for (int v = 0; v < 8; ++v) {
        acc[v] += __shfl_xor(acc[v], 8);
        acc[v] += __shfl_xor(acc[v], 16);
        acc[v] += __shfl_xor(acc[v], 32);
    }

    int c = cg * 8 + q;
    float o = acc[q] + bias[c];
    if (RELU) o = fmaxf(o, 0.f);
    OUT[(size_t)node * 64 + c] = o;
}

static inline size_t align_up(size_t x) { return (x + 255) & ~size_t(255); }

extern "C" void kernel_launch(void* const* d_in, const int* in_sizes, int n_in,
                              void* d_out, int out_size, void* d_ws, size_t ws_size,
                              hipStream_t stream)
{
    const float* x  = (const float*)d_in[0];
    const int*   ei = (const int*)d_in[1];
    const float* ew = (const float*)d_in[2];
    const float* W1 = (const float*)d_in[3];
    const float* b1 = (const float*)d_in[4];
    const float* W2 = (const float*)d_in[5];
    const float* b2 = (const float*)d_in[6];
    float* out = (float*)d_out;

    const int N = N_NODES;
    const int E = in_sizes[2];
    const int* src = ei;
    const int* dst = ei + E;

    const int NBLK = (E + CHUNK - 1) / CHUNK;          // 782 for E=1.6M
    const size_t REGION = (size_t)NBUCK * CAP;         // uint2 elements

    char* ws = (char*)d_ws;
    int*   histmat   = (int*)ws;   ws += align_up((size_t)NBLK * 256 * 4);
    int*   bucketSize= (int*)ws;   ws += align_up((size_t)NBUCK * 4);
    float* dinv      = (float*)ws; ws += align_up((size_t)N * 4);
    uint2* nodeinfo  = (uint2*)ws; ws += align_up((size_t)N * 8);
    uint2* csrTmp    = (uint2*)ws; ws += align_up(REGION * 8);
    uint2* csrF      = (uint2*)ws; ws += align_up(REGION * 8);
    unsigned* h1     = (unsigned*)ws; ws += align_up((size_t)N * 128 * 2); // bf16 packed
    float*    g1     = (float*)ws;    ws += align_up((size_t)N * 128 * 4);
    unsigned* h2     = (unsigned*)ws; ws += align_up((size_t)N * 64 * 2);  // bf16 packed

    // ---- CSR build (no global atomics, no memsets) ----
    partA1_kernel<<<NBLK, 256, 0, stream>>>(dst, histmat, E);
    scanB_kernel<<<NBUCK, 256, 0, stream>>>(histmat, bucketSize, NBLK);
    partA2_kernel<<<NBLK, 256, 0, stream>>>(src, dst, ew, histmat, csrTmp, E);
    bucketB1_kernel<<<NBUCK, 1024, 0, stream>>>(csrTmp, bucketSize, dinv, nodeinfo, N);
    bucketB2_kernel<<<NBUCK, 1024, 0, stream>>>(csrTmp, bucketSize, nodeinfo, dinv, csrF, N);

    // ---- layer 1 ----
    gemm_kernel<128><<<(N + 63) / 64, 256, 0, stream>>>(x, W1, h1, N);
    gather128_kernel<true><<<(N + 3) / 4, 256, 0, stream>>>(
        nodeinfo, csrF, (const uint4*)h1, dinv, b1, g1, N);

    // ---- layer 2 ----
    gemm_kernel<64><<<(N + 63) / 64, 256, 0, stream>>>(g1, W2, h2, N);
    gather64_kernel<false><<<(N + 3) / 4, 256, 0, stream>>>(
        nodeinfo, csrF, (const uint4*)h2, dinv, b2, out, N);
}

// Round 7
// 297.377 us; speedup vs baseline: 14.6517x; 1.1430x over previous
//
#include <hip/hip_runtime.h>

// ---------------------------------------------------------------------------
// Two-layer GCN on MI355X.  Round 7: bf16 MFMA GEMM (16x16x32), replacing the
// fp32 vector GEMM (69us -> ~15us).  W pre-transposed/packed to B-operand
// [n][k] layout by prep_w; X staged fp32->bf16 (layer1) or consumed as
// packed bf16 (layer2, written directly by gather128).  CSR build (two-level
// counting sort) and register-accumulating gathers carried from R6.
// ---------------------------------------------------------------------------

#define N_NODES 100000
#define CHUNK   2048
#define NBUCK   196
#define BSHIFT  9
#define BNODES  512
#define CAP     10240

typedef __attribute__((ext_vector_type(8))) short bf16x8;   // 8 bf16 (4 VGPRs)
typedef __attribute__((ext_vector_type(4))) float f32x4;    // 4 fp32 acc

__device__ __forceinline__ unsigned bf16r(float f) {
    unsigned u = __float_as_uint(f);
    return (u + 0x7fffu + ((u >> 16) & 1u)) >> 16;     // RNE
}
__device__ __forceinline__ float bf_lo(unsigned u) { return __uint_as_float(u << 16); }
__device__ __forceinline__ float bf_hi(unsigned u) { return __uint_as_float(u & 0xffff0000u); }

// ---- A1: per-block histogram over buckets ---------------------------------

__global__ __launch_bounds__(256) void partA1_kernel(
    const int* __restrict__ dst, int* __restrict__ histmat, int E)
{
    __shared__ int hist[256];
    int t = threadIdx.x, blk = blockIdx.x;
    hist[t] = 0;
    __syncthreads();
    int e0 = blk * CHUNK;
    int nv = min(CHUNK, E - e0);
#pragma unroll
    for (int j = 0; j < CHUNK / 256; ++j) {
        int idx = t + j * 256;
        if (idx < nv) atomicAdd(&hist[dst[e0 + idx] >> BSHIFT], 1);
    }
    __syncthreads();
    histmat[blk * 256 + t] = hist[t];
}

// ---- scanB: per-bucket exclusive scan over block rows ---------------------

__global__ __launch_bounds__(256) void scanB_kernel(
    int* __restrict__ histmat, int* __restrict__ bucketSize, int NBLK)
{
    __shared__ int sums[256];
    int b = blockIdx.x, t = threadIdx.x;
    const int PER = (NBLK + 255) / 256;
    int loc[8];
    int s = 0;
#pragma unroll 8
    for (int j = 0; j < PER; ++j) {
        int r = t * PER + j;
        int v = (r < NBLK) ? histmat[r * 256 + b] : 0;
        loc[j] = v; s += v;
    }
    sums[t] = s;
    __syncthreads();
    int v = s;
#pragma unroll
    for (int off = 1; off < 256; off <<= 1) {
        int a = (t >= off) ? sums[t - off] : 0;
        __syncthreads();
        sums[t] += a;
        __syncthreads();
    }
    if (t == 255) bucketSize[b] = sums[255];
    int run = sums[t] - v;
#pragma unroll 8
    for (int j = 0; j < PER; ++j) {
        int r = t * PER + j;
        if (r < NBLK) { histmat[r * 256 + b] = run; run += loc[j]; }
    }
}

// ---- A2: reorder block's edges by bucket, write grouped runs --------------

__global__ __launch_bounds__(256) void partA2_kernel(
    const int* __restrict__ src, const int* __restrict__ dst,
    const float* __restrict__ ew, const int* __restrict__ histmat,
    uint2* __restrict__ csrTmp, int E)
{
    __shared__ int hist[256], sc[256], exc[256], lcur[256], basel[256];
    __shared__ uint2 ent[CHUNK];
    __shared__ unsigned short bof[CHUNK];

    int t = threadIdx.x, blk = blockIdx.x;
    hist[t] = 0; lcur[t] = 0;
    basel[t] = histmat[blk * 256 + t];
    __syncthreads();

    int e0 = blk * CHUNK;
    int nv = min(CHUNK, E - e0);
    int dv[CHUNK / 256]; int sv[CHUNK / 256]; unsigned wv[CHUNK / 256];
#pragma unroll
    for (int j = 0; j < CHUNK / 256; ++j) {
        int idx = t + j * 256;
        if (idx < nv) {
            int e = e0 + idx;
            dv[j] = dst[e]; sv[j] = src[e]; wv[j] = __float_as_uint(ew[e]);
            atomicAdd(&hist[dv[j] >> BSHIFT], 1);
        } else dv[j] = -1;
    }
    __syncthreads();
    int hv = hist[t];
    sc[t] = hv;
    __syncthreads();
#pragma unroll
    for (int off = 1; off < 256; off <<= 1) {
        int a = (t >= off) ? sc[t - off] : 0;
        __syncthreads();
        sc[t] += a;
        __syncthreads();
    }
    exc[t] = sc[t] - hv;
    __syncthreads();
#pragma unroll
    for (int j = 0; j < CHUNK / 256; ++j) {
        if (dv[j] >= 0) {
            int b  = dv[j] >> BSHIFT;
            int dl = dv[j] & (BNODES - 1);
            int p  = exc[b] + atomicAdd(&lcur[b], 1);
            ent[p] = make_uint2(((unsigned)dl << 17) | (unsigned)sv[j], wv[j]);
            bof[p] = (unsigned short)b;
        }
    }
    __syncthreads();
#pragma unroll
    for (int j = 0; j < CHUNK / 256; ++j) {
        int i = t + j * 256;
        if (i < nv) {
            int b = bof[i];
            size_t addr = (size_t)b * CAP + basel[b] + (i - exc[b]);
            csrTmp[addr] = ent[i];
        }
    }
}

// ---- B1: per-bucket degree/count (LDS), dinv, nodeinfo --------------------

__global__ __launch_bounds__(1024) void bucketB1_kernel(
    const uint2* __restrict__ csrTmp, const int* __restrict__ bucketSize,
    float* __restrict__ dinv, uint2* __restrict__ nodeinfo, int N)
{
    __shared__ unsigned long long dc[BNODES];
    __shared__ int scn[BNODES];
    int b = blockIdx.x, t = threadIdx.x;
    if (t < BNODES) dc[t] = 0ull;
    __syncthreads();

    int sz = bucketSize[b];
    const uint2* reg = csrTmp + (size_t)b * CAP;
    for (int i = t; i < sz; i += 1024) {
        uint2 en = reg[i];
        int dl = (int)(en.x >> 17);
        unsigned fx = (unsigned)__float2uint_rn(__uint_as_float(en.y) * 16777216.0f);
        atomicAdd(&dc[dl], (1ull << 32) | (unsigned long long)fx);
    }
    __syncthreads();

    int cnt = 0; float dv = 1.0f;
    if (t < BNODES) {
        unsigned long long v = dc[t];
        cnt = (int)(v >> 32);
        float deg = (float)(unsigned)(v & 0xffffffffull) * (1.0f / 16777216.0f);
        dv = rsqrtf(deg + 1.0f);
        scn[t] = cnt;
    }
    __syncthreads();
#pragma unroll
    for (int off = 1; off < BNODES; off <<= 1) {
        int a = 0;
        if (t < BNODES && t >= off) a = scn[t - off];
        __syncthreads();
        if (t < BNODES) scn[t] += a;
        __syncthreads();
    }
    if (t < BNODES) {
        int excl = scn[t] - cnt;
        int gn = b * BNODES + t;
        if (gn < N) {
            dinv[gn] = dv;
            nodeinfo[gn] = make_uint2((unsigned)(b * CAP + excl), (unsigned)cnt);
        }
    }
}

// ---- B2: per-bucket local sort + fused norm weight ------------------------

__global__ __launch_bounds__(1024) void bucketB2_kernel(
    const uint2* __restrict__ csrTmp, const int* __restrict__ bucketSize,
    const uint2* __restrict__ nodeinfo, const float* __restrict__ dinv,
    uint2* __restrict__ csrF, int N)
{
    __shared__ float dinv_l[BNODES];
    __shared__ int beg[BNODES], cur[BNODES];
    int b = blockIdx.x, t = threadIdx.x;
    if (t < BNODES) {
        int gn = b * BNODES + t;
        float dv = 1.0f; int bg = 0;
        if (gn < N) { uint2 inf = nodeinfo[gn]; bg = (int)inf.x; dv = dinv[gn]; }
        dinv_l[t] = dv; beg[t] = bg; cur[t] = 0;
    }
    __syncthreads();

    int sz = bucketSize[b];
    const uint2* reg = csrTmp + (size_t)b * CAP;
    for (int i = t; i < sz; i += 1024) {
        uint2 en = reg[i];
        int dl = (int)(en.x >> 17);
        int s  = (int)(en.x & 0x1FFFFu);
        int p  = beg[dl] + atomicAdd(&cur[dl], 1);
        float w = dinv[s] * __uint_as_float(en.y) * dinv_l[dl];
        csrF[p] = make_uint2((unsigned)s, __float_as_uint(w));
    }
}

// ---- prep_w: W[k][c] fp32 -> Wt[c][j] = pack(W[2j][c], W[2j+1][c]) bf16 ---
// (B-operand wants [n][k] rows, k contiguous)

__global__ __launch_bounds__(256) void prep_w_kernel(
    const float* __restrict__ W1, const float* __restrict__ W2,
    unsigned* __restrict__ Wt1, unsigned* __restrict__ Wt2)
{
    int t = threadIdx.x;
    if (blockIdx.x == 0) {
        for (int f = t; f < 128 * 64; f += 256) {
            int c = f % 128, j = f / 128;
            unsigned p = bf16r(W1[(size_t)(2 * j) * 128 + c]) |
                         (bf16r(W1[(size_t)(2 * j + 1) * 128 + c]) << 16);
            Wt1[c * 64 + j] = p;
        }
    } else {
        for (int f = t; f < 64 * 64; f += 256) {
            int c = f % 64, j = f / 64;
            unsigned p = bf16r(W2[(size_t)(2 * j) * 64 + c]) |
                         (bf16r(W2[(size_t)(2 * j + 1) * 64 + c]) << 16);
            Wt2[c * 64 + j] = p;
        }
    }
}

// ---- MFMA GEMM: Hb(bf16 packed) = X @ W,  X: M x 128, W via Wt [NCOL][64] -
// Block: 256 thr / 4 waves, 64 rows, K=128 in one LDS residency.
// Wave computes 64x32 (NCOL=128) or 64x16 (NCOL=64): 4 m-tiles x NT n-tiles.
// LDS rows padded +4 uints -> 2-way bank aliasing (free).

template <int NCOL, bool XBF16>
__global__ __launch_bounds__(256) void gemm_mfma_kernel(
    const void* __restrict__ Xv, const unsigned* __restrict__ Wt,
    unsigned* __restrict__ Hb, int M)
{
    constexpr int KU  = 64;        // K/2 uints per row
    constexpr int LW  = KU + 4;    // padded row (uints)
    constexpr int NT  = (NCOL == 128) ? 2 : 1;
    __shared__ unsigned sA[64 * LW];
    __shared__ unsigned sB[NCOL * LW];

    const int t = threadIdx.x;
    const int rbase = blockIdx.x * 64;

    // stage B (already bf16-packed, [n][k])
    for (int f = t; f < NCOL * (KU / 4); f += 256) {
        int c = f / (KU / 4), q = f % (KU / 4);
        uint4 v = *(const uint4*)&Wt[c * KU + q * 4];
        *(uint4*)&sB[c * LW + q * 4] = v;
    }
    // stage A
    if (XBF16) {
        const unsigned* Xu = (const unsigned*)Xv;
        for (int f = t; f < 64 * (KU / 4); f += 256) {
            int r = f / (KU / 4), q = f % (KU / 4);
            int gr = rbase + r;
            uint4 v = make_uint4(0, 0, 0, 0);
            if (gr < M) v = *(const uint4*)&Xu[(size_t)gr * KU + q * 4];
            *(uint4*)&sA[r * LW + q * 4] = v;
        }
    } else {
        const float* Xf = (const float*)Xv;
        for (int f = t; f < 64 * 32; f += 256) {      // 32 float4 per row
            int r = f / 32, c4 = f % 32;
            int gr = rbase + r;
            float4 v = make_float4(0.f, 0.f, 0.f, 0.f);
            if (gr < M) v = *(const float4*)&Xf[(size_t)gr * 128 + c4 * 4];
            sA[r * LW + c4 * 2]     = bf16r(v.x) | (bf16r(v.y) << 16);
            sA[r * LW + c4 * 2 + 1] = bf16r(v.z) | (bf16r(v.w) << 16);
        }
    }
    __syncthreads();

    const int wave = t >> 6, lane = t & 63;
    const int quad = lane >> 4, lr = lane & 15;
    const int n0 = wave * (16 * NT);

    f32x4 acc[4][NT];
#pragma unroll
    for (int mi = 0; mi < 4; ++mi)
#pragma unroll
        for (int ni = 0; ni < NT; ++ni)
            acc[mi][ni] = (f32x4){0.f, 0.f, 0.f, 0.f};

#pragma unroll
    for (int ks = 0; ks < 4; ++ks) {
        int ko = ks * 16 + quad * 4;                  // uint offset = k/2
        bf16x8 b[NT];
#pragma unroll
        for (int ni = 0; ni < NT; ++ni)
            b[ni] = *(const bf16x8*)&sB[(n0 + ni * 16 + lr) * LW + ko];
#pragma unroll
        for (int mi = 0; mi < 4; ++mi) {
            bf16x8 a = *(const bf16x8*)&sA[(mi * 16 + lr) * LW + ko];
#pragma unroll
            for (int ni = 0; ni < NT; ++ni)
                acc[mi][ni] = __builtin_amdgcn_mfma_f32_16x16x32_bf16(
                    a, b[ni], acc[mi][ni], 0, 0, 0);
        }
    }
    __syncthreads();          // done with sA as input; reuse as epilogue buf

    // C/D layout: col = lane&15, row = quad*4 + reg  -> LDS, then coalesced
    unsigned short* sO = (unsigned short*)sA;         // [64][2*LW] ushorts
#pragma unroll
    for (int mi = 0; mi < 4; ++mi)
#pragma unroll
        for (int ni = 0; ni < NT; ++ni)
#pragma unroll
            for (int r = 0; r < 4; ++r)
                sO[(mi * 16 + quad * 4 + r) * (2 * LW) + n0 + ni * 16 + lr] =
                    (unsigned short)bf16r(acc[mi][ni][r]);
    __syncthreads();

    for (int f = t; f < 64 * (NCOL / 2); f += 256) {
        int row = f / (NCOL / 2), cu = f % (NCOL / 2);
        int gr = rbase + row;
        if (gr < M) Hb[(size_t)gr * (NCOL / 2) + cu] = sA[row * LW + cu];
    }
}

// ---- gather C=128 (layer 1): writes packed-bf16 g1, fused bias+ReLU -------

__global__ __launch_bounds__(256) void gather128_kernel(
    const uint2* __restrict__ nodeinfo, const uint2* __restrict__ csr,
    const uint4* __restrict__ Hb4,                 // row = 16 uint4
    const float* __restrict__ dinv, const float* __restrict__ bias,
    unsigned* __restrict__ OUTP, int N)
{
    int node = blockIdx.x * 4 + (threadIdx.x >> 6);
    if (node >= N) return;
    int lane = threadIdx.x & 63;
    int q  = lane >> 4;
    int cg = lane & 15;

    float d2; { float di = dinv[node]; d2 = (q == 0) ? di * di : 0.f; }
    float acc[8];
    {
        uint4 su = Hb4[(size_t)node * 16 + cg];
        acc[0] = bf_lo(su.x) * d2; acc[1] = bf_hi(su.x) * d2;
        acc[2] = bf_lo(su.y) * d2; acc[3] = bf_hi(su.y) * d2;
        acc[4] = bf_lo(su.z) * d2; acc[5] = bf_hi(su.z) * d2;
        acc[6] = bf_lo(su.w) * d2; acc[7] = bf_hi(su.w) * d2;
    }

    uint2 inf = nodeinfo[node];
    int beg = (int)inf.x, end = beg + (int)inf.y;
    for (int j = beg; j < end; j += 64) {
        int cs = 0, cw = 0;
        if (j + lane < end) {
            uint2 p = csr[j + lane];
            cs = (int)p.x; cw = (int)p.y;
        }
        int mm = end - j; if (mm > 64) mm = 64;
#pragma unroll 4
        for (int k = 0; k < mm; k += 4) {
            int   idx = k + q;
            int   s = __shfl(cs, idx);
            float w = __uint_as_float(__shfl(cw, idx));
            uint4 u = Hb4[(size_t)s * 16 + cg];
            acc[0] = fmaf(bf_lo(u.x), w, acc[0]); acc[1] = fmaf(bf_hi(u.x), w, acc[1]);
            acc[2] = fmaf(bf_lo(u.y), w, acc[2]); acc[3] = fmaf(bf_hi(u.y), w, acc[3]);
            acc[4] = fmaf(bf_lo(u.z), w, acc[4]); acc[5] = fmaf(bf_hi(u.z), w, acc[5]);
            acc[6] = fmaf(bf_lo(u.w), w, acc[6]); acc[7] = fmaf(bf_hi(u.w), w, acc[7]);
        }
    }

#pragma unroll
    for (int v = 0; v < 8; ++v) {
        acc[v] += __shfl_xor(acc[v], 16);
        acc[v] += __shfl_xor(acc[v], 32);
    }

    int c = cg * 8 + q * 2;
    float o0 = fmaxf(acc[q * 2]     + bias[c],     0.f);
    float o1 = fmaxf(acc[q * 2 + 1] + bias[c + 1], 0.f);
    OUTP[(size_t)node * 64 + cg * 4 + q] = bf16r(o0) | (bf16r(o1) << 16);
}

// ---- gather C=64 (layer 2): fp32 final output -----------------------------

__global__ __launch_bounds__(256) void gather64_kernel(
    const uint2* __restrict__ nodeinfo, const uint2* __restrict__ csr,
    const uint4* __restrict__ Hb4,                 // row = 8 uint4
    const float* __restrict__ dinv, const float* __restrict__ bias,
    float* __restrict__ OUT, int N)
{
    int node = blockIdx.x * 4 + (threadIdx.x >> 6);
    if (node >= N) return;
    int lane = threadIdx.x & 63;
    int q  = lane >> 3;
    int cg = lane & 7;

    float d2; { float di = dinv[node]; d2 = (q == 0) ? di * di : 0.f; }
    float acc[8];
    {
        uint4 su = Hb4[(size_t)node * 8 + cg];
        acc[0] = bf_lo(su.x) * d2; acc[1] = bf_hi(su.x) * d2;
        acc[2] = bf_lo(su.y) * d2; acc[3] = bf_hi(su.y) * d2;
        acc[4] = bf_lo(su.z) * d2; acc[5] = bf_hi(su.z) * d2;
        acc[6] = bf_lo(su.w) * d2; acc[7] = bf_hi(su.w) * d2;
    }

    uint2 inf = nodeinfo[node];
    int beg = (int)inf.x, end = beg + (int)inf.y;
    for (int j = beg; j < end; j += 64) {
        int cs = 0, cw = 0;
        if (j + lane < end) {
            uint2 p = csr[j + lane];
            cs = (int)p.x; cw = (int)p.y;
        }
        int mm = end - j; if (mm > 64) mm = 64;
#pragma unroll 2
        for (int k = 0; k < mm; k += 8) {
            int   idx = k + q;
            int   s = __shfl(cs, idx);
            float w = __uint_as_float(__shfl(cw, idx));
            uint4 u = Hb4[(size_t)s * 8 + cg];
            acc[0] = fmaf(bf_lo(u.x), w, acc[0]); acc[1] = fmaf(bf_hi(u.x), w, acc[1]);
            acc[2] = fmaf(bf_lo(u.y), w, acc[2]); acc[3] = fmaf(bf_hi(u.y), w, acc[3]);
            acc[4] = fmaf(bf_lo(u.z), w, acc[4]); acc[5] = fmaf(bf_hi(u.z), w, acc[5]);
            acc[6] = fmaf(bf_lo(u.w), w, acc[6]); acc[7] = fmaf(bf_hi(u.w), w, acc[7]);
        }
    }

#pragma unroll
    for (int v = 0; v < 8; ++v) {
        acc[v] += __shfl_xor(acc[v], 8);
        acc[v] += __shfl_xor(acc[v], 16);
        acc[v] += __shfl_xor(acc[v], 32);
    }

    int c = cg * 8 + q;
    OUT[(size_t)node * 64 + c] = acc[q] + bias[c];
}

static inline size_t align_up(size_t x) { return (x + 255) & ~size_t(255); }

extern "C" void kernel_launch(void* const* d_in, const int* in_sizes, int n_in,
                              void* d_out, int out_size, void* d_ws, size_t ws_size,
                              hipStream_t stream)
{
    const float* x  = (const float*)d_in[0];
    const int*   ei = (const int*)d_in[1];
    const float* ew = (const float*)d_in[2];
    const float* W1 = (const float*)d_in[3];
    const float* b1 = (const float*)d_in[4];
    const float* W2 = (const float*)d_in[5];
    const float* b2 = (const float*)d_in[6];
    float* out = (float*)d_out;

    const int N = N_NODES;
    const int E = in_sizes[2];
    const int* src = ei;
    const int* dst = ei + E;

    const int NBLK = (E + CHUNK - 1) / CHUNK;
    const size_t REGION = (size_t)NBUCK * CAP;

    char* ws = (char*)d_ws;
    int*   histmat   = (int*)ws;   ws += align_up((size_t)NBLK * 256 * 4);
    int*   bucketSize= (int*)ws;   ws += align_up((size_t)NBUCK * 4);
    float* dinv      = (float*)ws; ws += align_up((size_t)N * 4);
    uint2* nodeinfo  = (uint2*)ws; ws += align_up((size_t)N * 8);
    uint2* csrTmp    = (uint2*)ws; ws += align_up(REGION * 8);
    uint2* csrF      = (uint2*)ws; ws += align_up(REGION * 8);
    unsigned* Wt1    = (unsigned*)ws; ws += align_up((size_t)128 * 64 * 4);
    unsigned* Wt2    = (unsigned*)ws; ws += align_up((size_t)64 * 64 * 4);
    unsigned* h1     = (unsigned*)ws; ws += align_up((size_t)N * 64 * 4);  // bf16 pk
    unsigned* g1     = (unsigned*)ws; ws += align_up((size_t)N * 64 * 4);  // bf16 pk
    unsigned* h2     = (unsigned*)ws; ws += align_up((size_t)N * 32 * 4);  // bf16 pk

    // ---- CSR build + weight prep ----
    prep_w_kernel<<<2, 256, 0, stream>>>(W1, W2, Wt1, Wt2);
    partA1_kernel<<<NBLK, 256, 0, stream>>>(dst, histmat, E);
    scanB_kernel<<<NBUCK, 256, 0, stream>>>(histmat, bucketSize, NBLK);
    partA2_kernel<<<NBLK, 256, 0, stream>>>(src, dst, ew, histmat, csrTmp, E);
    bucketB1_kernel<<<NBUCK, 1024, 0, stream>>>(csrTmp, bucketSize, dinv, nodeinfo, N);
    bucketB2_kernel<<<NBUCK, 1024, 0, stream>>>(csrTmp, bucketSize, nodeinfo, dinv, csrF, N);

    // ---- layer 1 ----
    gemm_mfma_kernel<128, false><<<(N + 63) / 64, 256, 0, stream>>>(x, Wt1, h1, N);
    gather128_kernel<<<(N + 3) / 4, 256, 0, stream>>>(
        nodeinfo, csrF, (const uint4*)h1, dinv, b1, g1, N);

    // ---- layer 2 ----
    gemm_mfma_kernel<64, true><<<(N + 63) / 64, 256, 0, stream>>>(g1, Wt2, h2, N);
    gather64_kernel<<<(N + 3) / 4, 256, 0, stream>>>(
        nodeinfo, csrF, (const uint4*)h2, dinv, b2, out, N);
}

// Round 8
// 289.061 us; speedup vs baseline: 15.0732x; 1.0288x over previous
//
#include <hip/hip_runtime.h>

// ---------------------------------------------------------------------------
// Two-layer GCN on MI355X.  Round 8: 6-dispatch pipeline.
//   identity: out[d] = dinv[d]*( sum_e ew*dinv[s]*h[s] + dinv[d]*h[d] ) + b
//   -> CSR stores {s, ew} only; dinv[s] applied in gather (L2-hot 4B load).
//   1. prepA1  : W1/W2 bf16 B-layout pack (2 blks) + per-block dst histogram
//   2. scanB   : per-bucket scan over blocks
//   3. a2_gemm : A2 bucket-reorder blocks + gemm1 (x@W1, MFMA) blocks, fused
//   4. bucketB : B1+B2 merged; bucket staged in LDS (80KB); dinv, nodeinfo,
//                node-sorted csrF in one pass
//   5. gg      : gather128 + bias/relu + MFMA gemm2 (h2 = g1@W2) fused;
//                writes h2 bf16-packed; g1 never materialized
//   6. gather64: gather h2 + bias -> out fp32
// ---------------------------------------------------------------------------

#define N_NODES 100000
#define CHUNK   2048
#define NBUCK   196
#define BSHIFT  9
#define BNODES  512
#define CAP     10240

typedef __attribute__((ext_vector_type(8))) short bf16x8;
typedef __attribute__((ext_vector_type(4))) float f32x4;

__device__ __forceinline__ unsigned bf16r(float f) {
    unsigned u = __float_as_uint(f);
    return (u + 0x7fffu + ((u >> 16) & 1u)) >> 16;     // RNE
}
__device__ __forceinline__ float bf_lo(unsigned u) { return __uint_as_float(u << 16); }
__device__ __forceinline__ float bf_hi(unsigned u) { return __uint_as_float(u & 0xffff0000u); }

// ---- 1. prepA1: W-pack (blocks 0,1) + per-block bucket histogram ----------

__global__ __launch_bounds__(256) void prepA1_kernel(
    const int* __restrict__ dst, const float* __restrict__ W1,
    const float* __restrict__ W2, unsigned* __restrict__ Wt1,
    unsigned* __restrict__ Wt2, int* __restrict__ histmat, int E)
{
    __shared__ int hist[256];
    int t = threadIdx.x;
    if (blockIdx.x == 0) {
        for (int f = t; f < 128 * 64; f += 256) {
            int c = f % 128, j = f / 128;
            Wt1[c * 64 + j] = bf16r(W1[(size_t)(2 * j) * 128 + c]) |
                              (bf16r(W1[(size_t)(2 * j + 1) * 128 + c]) << 16);
        }
        return;
    }
    if (blockIdx.x == 1) {
        for (int f = t; f < 64 * 64; f += 256) {
            int c = f % 64, j = f / 64;
            Wt2[c * 64 + j] = bf16r(W2[(size_t)(2 * j) * 64 + c]) |
                              (bf16r(W2[(size_t)(2 * j + 1) * 64 + c]) << 16);
        }
        return;
    }
    int blk = blockIdx.x - 2;
    hist[t] = 0;
    __syncthreads();
    int e0 = blk * CHUNK;
    int nv = min(CHUNK, E - e0);
#pragma unroll
    for (int j = 0; j < CHUNK / 256; ++j) {
        int idx = t + j * 256;
        if (idx < nv) atomicAdd(&hist[dst[e0 + idx] >> BSHIFT], 1);
    }
    __syncthreads();
    histmat[blk * 256 + t] = hist[t];
}

// ---- 2. scanB -------------------------------------------------------------

__global__ __launch_bounds__(256) void scanB_kernel(
    int* __restrict__ histmat, int* __restrict__ bucketSize, int NBLK)
{
    __shared__ int sums[256];
    int b = blockIdx.x, t = threadIdx.x;
    const int PER = (NBLK + 255) / 256;
    int loc[8];
    int s = 0;
#pragma unroll 8
    for (int j = 0; j < PER; ++j) {
        int r = t * PER + j;
        int v = (r < NBLK) ? histmat[r * 256 + b] : 0;
        loc[j] = v; s += v;
    }
    sums[t] = s;
    __syncthreads();
    int v = s;
#pragma unroll
    for (int off = 1; off < 256; off <<= 1) {
        int a = (t >= off) ? sums[t - off] : 0;
        __syncthreads();
        sums[t] += a;
        __syncthreads();
    }
    if (t == 255) bucketSize[b] = sums[255];
    int run = sums[t] - v;
#pragma unroll 8
    for (int j = 0; j < PER; ++j) {
        int r = t * PER + j;
        if (r < NBLK) { histmat[r * 256 + b] = run; run += loc[j]; }
    }
}

// ---- 3. a2_gemm: A2 reorder blocks + gemm1 blocks (union smem) ------------

#define A2G_SMEM 52224     // gemm: 64*68*4 + 128*68*4 ; a2 needs 25600

__device__ __forceinline__ void a2_body(
    char* smem, int blk,
    const int* __restrict__ src, const int* __restrict__ dst,
    const float* __restrict__ ew, const int* __restrict__ histmat,
    uint2* __restrict__ csrTmp, int E)
{
    int* hist = (int*)smem;
    int* sc   = hist + 256;
    int* exc  = sc + 256;
    int* lcur = exc + 256;
    int* basel= lcur + 256;
    uint2* ent = (uint2*)(basel + 256);
    unsigned short* bof = (unsigned short*)(ent + CHUNK);

    int t = threadIdx.x;
    hist[t] = 0; lcur[t] = 0;
    basel[t] = histmat[blk * 256 + t];
    __syncthreads();

    int e0 = blk * CHUNK;
    int nv = min(CHUNK, E - e0);
    int dv[CHUNK / 256]; int sv[CHUNK / 256]; unsigned wv[CHUNK / 256];
#pragma unroll
    for (int j = 0; j < CHUNK / 256; ++j) {
        int idx = t + j * 256;
        if (idx < nv) {
            int e = e0 + idx;
            dv[j] = dst[e]; sv[j] = src[e]; wv[j] = __float_as_uint(ew[e]);
            atomicAdd(&hist[dv[j] >> BSHIFT], 1);
        } else dv[j] = -1;
    }
    __syncthreads();
    int hv = hist[t];
    sc[t] = hv;
    __syncthreads();
#pragma unroll
    for (int off = 1; off < 256; off <<= 1) {
        int a = (t >= off) ? sc[t - off] : 0;
        __syncthreads();
        sc[t] += a;
        __syncthreads();
    }
    exc[t] = sc[t] - hv;
    __syncthreads();
#pragma unroll
    for (int j = 0; j < CHUNK / 256; ++j) {
        if (dv[j] >= 0) {
            int b  = dv[j] >> BSHIFT;
            int dl = dv[j] & (BNODES - 1);
            int p  = exc[b] + atomicAdd(&lcur[b], 1);
            ent[p] = make_uint2(((unsigned)dl << 17) | (unsigned)sv[j], wv[j]);
            bof[p] = (unsigned short)b;
        }
    }
    __syncthreads();
#pragma unroll
    for (int j = 0; j < CHUNK / 256; ++j) {
        int i = t + j * 256;
        if (i < nv) {
            int b = bof[i];
            csrTmp[(size_t)b * CAP + basel[b] + (i - exc[b])] = ent[i];
        }
    }
}

__device__ __forceinline__ void gemm1_body(
    char* smem, int blk, const float* __restrict__ Xf,
    const unsigned* __restrict__ Wt, unsigned* __restrict__ Hb, int M)
{
    constexpr int LW = 68, KU = 64;
    unsigned* sA = (unsigned*)smem;            // 64 x LW
    unsigned* sB = sA + 64 * LW;               // 128 x LW
    const int t = threadIdx.x;
    const int rbase = blk * 64;

    for (int f = t; f < 128 * 16; f += 256) {  // B: 128 rows x 16 uint4
        int c = f >> 4, qd = f & 15;
        *(uint4*)&sB[c * LW + qd * 4] = *(const uint4*)&Wt[c * KU + qd * 4];
    }
    for (int f = t; f < 64 * 32; f += 256) {   // A: fp32 -> bf16 pack
        int r = f >> 5, c4 = f & 31;
        int gr = rbase + r;
        float4 v = make_float4(0.f, 0.f, 0.f, 0.f);
        if (gr < M) v = *(const float4*)&Xf[(size_t)gr * 128 + c4 * 4];
        sA[r * LW + c4 * 2]     = bf16r(v.x) | (bf16r(v.y) << 16);
        sA[r * LW + c4 * 2 + 1] = bf16r(v.z) | (bf16r(v.w) << 16);
    }
    __syncthreads();

    const int wave = t >> 6, lane = t & 63;
    const int quad = lane >> 4, lr = lane & 15;
    const int n0 = wave * 32;

    f32x4 acc[4][2];
#pragma unroll
    for (int mi = 0; mi < 4; ++mi)
#pragma unroll
        for (int ni = 0; ni < 2; ++ni)
            acc[mi][ni] = (f32x4){0.f, 0.f, 0.f, 0.f};

#pragma unroll
    for (int ks = 0; ks < 4; ++ks) {
        int ko = ks * 16 + quad * 4;
        bf16x8 b0 = *(const bf16x8*)&sB[(n0 + lr) * LW + ko];
        bf16x8 b1 = *(const bf16x8*)&sB[(n0 + 16 + lr) * LW + ko];
#pragma unroll
        for (int mi = 0; mi < 4; ++mi) {
            bf16x8 a = *(const bf16x8*)&sA[(mi * 16 + lr) * LW + ko];
            acc[mi][0] = __builtin_amdgcn_mfma_f32_16x16x32_bf16(a, b0, acc[mi][0], 0, 0, 0);
            acc[mi][1] = __builtin_amdgcn_mfma_f32_16x16x32_bf16(a, b1, acc[mi][1], 0, 0, 0);
        }
    }
    __syncthreads();

    unsigned short* sO = (unsigned short*)sA;          // [64][2*LW]
#pragma unroll
    for (int mi = 0; mi < 4; ++mi)
#pragma unroll
        for (int ni = 0; ni < 2; ++ni)
#pragma unroll
            for (int r = 0; r < 4; ++r)
                sO[(mi * 16 + quad * 4 + r) * (2 * LW) + n0 + ni * 16 + lr] =
                    (unsigned short)bf16r(acc[mi][ni][r]);
    __syncthreads();

    for (int f = t; f < 64 * 64; f += 256) {
        int row = f >> 6, cu = f & 63;
        int gr = rbase + row;
        if (gr < M) Hb[(size_t)gr * 64 + cu] = sA[row * LW + cu];
    }
}

__global__ __launch_bounds__(256) void a2_gemm_kernel(
    const int* __restrict__ src, const int* __restrict__ dst,
    const float* __restrict__ ew, const int* __restrict__ histmat,
    uint2* __restrict__ csrTmp, int E, int NBLK,
    const float* __restrict__ x, const unsigned* __restrict__ Wt1,
    unsigned* __restrict__ h1, int M)
{
    __shared__ __align__(16) char smem[A2G_SMEM];
    if ((int)blockIdx.x < NBLK)
        a2_body(smem, blockIdx.x, src, dst, ew, histmat, csrTmp, E);
    else
        gemm1_body(smem, blockIdx.x - NBLK, x, Wt1, h1, M);
}

// ---- 4. bucketB: merged B1+B2, bucket staged in LDS -----------------------

__global__ __launch_bounds__(1024) void bucketB_kernel(
    const uint2* __restrict__ csrTmp, const int* __restrict__ bucketSize,
    float* __restrict__ dinv, uint2* __restrict__ nodeinfo,
    uint2* __restrict__ csrF, int N)
{
    __shared__ uint2 ent[CAP];                       // 80 KB
    __shared__ unsigned long long dc[BNODES];        // 4 KB
    __shared__ int scn[BNODES], beg[BNODES], cur[BNODES];
    int b = blockIdx.x, t = threadIdx.x;
    if (t < BNODES) { dc[t] = 0ull; cur[t] = 0; }
    __syncthreads();

    int sz = min(bucketSize[b], CAP);
    const uint2* reg = csrTmp + (size_t)b * CAP;
    for (int i = t; i < sz; i += 1024) {
        uint2 en = reg[i];
        ent[i] = en;
        int dl = (int)(en.x >> 17);
        unsigned fx = (unsigned)__float2uint_rn(__uint_as_float(en.y) * 16777216.0f);
        atomicAdd(&dc[dl], (1ull << 32) | (unsigned long long)fx);
    }
    __syncthreads();

    int cnt = 0; float dv = 1.0f;
    if (t < BNODES) {
        unsigned long long v = dc[t];
        cnt = (int)(v >> 32);
        dv = rsqrtf((float)(unsigned)(v & 0xffffffffull) * (1.0f / 16777216.0f) + 1.0f);
        scn[t] = cnt;
    }
    __syncthreads();
#pragma unroll
    for (int off = 1; off < BNODES; off <<= 1) {
        int a = 0;
        if (t < BNODES && t >= off) a = scn[t - off];
        __syncthreads();
        if (t < BNODES) scn[t] += a;
        __syncthreads();
    }
    if (t < BNODES) {
        int excl = scn[t] - cnt;
        beg[t] = excl;
        int gn = b * BNODES + t;
        if (gn < N) {
            dinv[gn] = dv;
            nodeinfo[gn] = make_uint2((unsigned)(b * CAP + excl), (unsigned)cnt);
        }
    }
    __syncthreads();

    uint2* outreg = csrF + (size_t)b * CAP;
    for (int i = t; i < sz; i += 1024) {
        uint2 en = ent[i];
        int dl = (int)(en.x >> 17);
        int p  = beg[dl] + atomicAdd(&cur[dl], 1);
        outreg[p] = make_uint2(en.x & 0x1FFFFu, en.y);   // {src, ew}
    }
}

// ---- 5. gg: gather128 (+bias+relu) + MFMA gemm2 fused ---------------------
// Block = 256 thr / 4 waves, 16 nodes (4 per wave, serial).
// Per node: wave = 4 edge-slots x 16 chan-groups, uint4 bf16 row loads,
// w = ew*dinv[src]; reduce; o = acc*dinv[d]+b1, relu; q0 lanes -> LDS tile.
// Then h2(16x64) = g1tile @ W2 via 4 MFMA per wave; packed bf16 out.

__global__ __launch_bounds__(256) void gg_kernel(
    const uint2* __restrict__ nodeinfo, const uint2* __restrict__ csr,
    const uint4* __restrict__ Hb4,                 // h1 row = 16 uint4
    const float* __restrict__ dinv, const float* __restrict__ bias,
    const unsigned* __restrict__ Wt2, unsigned* __restrict__ H2, int N)
{
    __shared__ __align__(16) unsigned sG[16 * 68];   // g1 tile bf16-packed
    __shared__ __align__(16) float    sO[16 * 68];   // h2 fp32 tile

    const int t = threadIdx.x, wave = t >> 6, lane = t & 63;
    const int q = lane >> 4, cg = lane & 15;
    const int nb = blockIdx.x * 16;

    for (int i = 0; i < 4; ++i) {
        int m = wave * 4 + i;
        int node = nb + m;                 // 6250*16 == 100000: no tail
        float di = dinv[node];
        float d0 = (q == 0) ? di : 0.f;    // self-loop only in slot 0
        float acc[8];
        {
            uint4 su = Hb4[(size_t)node * 16 + cg];
            acc[0] = bf_lo(su.x) * d0; acc[1] = bf_hi(su.x) * d0;
            acc[2] = bf_lo(su.y) * d0; acc[3] = bf_hi(su.y) * d0;
            acc[4] = bf_lo(su.z) * d0; acc[5] = bf_hi(su.z) * d0;
            acc[6] = bf_lo(su.w) * d0; acc[7] = bf_hi(su.w) * d0;
        }
        uint2 inf = nodeinfo[node];
        int beg = (int)inf.x, end = beg + (int)inf.y;
        for (int j = beg; j < end; j += 64) {
            int cs = 0; float cw = 0.f;
            if (j + lane < end) {
                uint2 p = csr[j + lane];
                cs = (int)p.x;
                cw = __uint_as_float(p.y) * dinv[cs];   // ew * dinv[src]
            }
            int mm = end - j; if (mm > 64) mm = 64;
#pragma unroll 4
            for (int k = 0; k < mm; k += 4) {
                int   s = __shfl(cs, k + q);
                float w = __shfl(cw, k + q);            // 0 beyond mm
                uint4 u = Hb4[(size_t)s * 16 + cg];
                acc[0] = fmaf(bf_lo(u.x), w, acc[0]); acc[1] = fmaf(bf_hi(u.x), w, acc[1]);
                acc[2] = fmaf(bf_lo(u.y), w, acc[2]); acc[3] = fmaf(bf_hi(u.y), w, acc[3]);
                acc[4] = fmaf(bf_lo(u.z), w, acc[4]); acc[5] = fmaf(bf_hi(u.z), w, acc[5]);
                acc[6] = fmaf(bf_lo(u.w), w, acc[6]); acc[7] = fmaf(bf_hi(u.w), w, acc[7]);
            }
        }
#pragma unroll
        for (int v = 0; v < 8; ++v) {
            acc[v] += __shfl_xor(acc[v], 16);
            acc[v] += __shfl_xor(acc[v], 32);
        }
        if (q == 0) {                      // full sums present in slot 0
            int c = cg * 8;
            uint4 pk;
            pk.x = bf16r(fmaxf(acc[0] * di + bias[c + 0], 0.f)) |
                   (bf16r(fmaxf(acc[1] * di + bias[c + 1], 0.f)) << 16);
            pk.y = bf16r(fmaxf(acc[2] * di + bias[c + 2], 0.f)) |
                   (bf16r(fmaxf(acc[3] * di + bias[c + 3], 0.f)) << 16);
            pk.z = bf16r(fmaxf(acc[4] * di + bias[c + 4], 0.f)) |
                   (bf16r(fmaxf(acc[5] * di + bias[c + 5], 0.f)) << 16);
            pk.w = bf16r(fmaxf(acc[6] * di + bias[c + 6], 0.f)) |
                   (bf16r(fmaxf(acc[7] * di + bias[c + 7], 0.f)) << 16);
            *(uint4*)&sG[m * 68 + cg * 4] = pk;
        }
    }
    __syncthreads();

    // h2 tile: wave handles n-tile n0 = wave*16
    {
        const int quad = lane >> 4, lr = lane & 15;
        const int n0 = wave * 16;
        f32x4 accv = (f32x4){0.f, 0.f, 0.f, 0.f};
#pragma unroll
        for (int ks = 0; ks < 4; ++ks) {
            int ko = ks * 16 + quad * 4;
            bf16x8 av = *(const bf16x8*)&sG[lr * 68 + ko];
            bf16x8 bv = *(const bf16x8*)&Wt2[(n0 + lr) * 64 + ko];
            accv = __builtin_amdgcn_mfma_f32_16x16x32_bf16(av, bv, accv, 0, 0, 0);
        }
#pragma unroll
        for (int r = 0; r < 4; ++r)
            sO[(quad * 4 + r) * 68 + n0 + lr] = accv[r];
    }
    __syncthreads();

    for (int f = t; f < 512; f += 256) {      // 16 rows x 32 packed uints
        int row = f >> 5, cu = f & 31;
        unsigned pk = bf16r(sO[row * 68 + 2 * cu]) |
                      (bf16r(sO[row * 68 + 2 * cu + 1]) << 16);
        H2[(size_t)(nb + row) * 32 + cu] = pk;
    }
}

// ---- 6. gather64: aggregate h2 -> out fp32 --------------------------------

__global__ __launch_bounds__(256) void gather64_kernel(
    const uint2* __restrict__ nodeinfo, const uint2* __restrict__ csr,
    const uint4* __restrict__ Hb4,                 // h2 row = 8 uint4
    const float* __restrict__ dinv, const float* __restrict__ bias,
    float* __restrict__ OUT, int N)
{
    int node = blockIdx.x * 4 + (threadIdx.x >> 6);
    if (node >= N) return;
    int lane = threadIdx.x & 63;
    int q  = lane >> 3;        // slot 0..7
    int cg = lane & 7;

    float di = dinv[node];
    float d0 = (q == 0) ? di : 0.f;
    float acc[8];
    {
        uint4 su = Hb4[(size_t)node * 8 + cg];
        acc[0] = bf_lo(su.x) * d0; acc[1] = bf_hi(su.x) * d0;
        acc[2] = bf_lo(su.y) * d0; acc[3] = bf_hi(su.y) * d0;
        acc[4] = bf_lo(su.z) * d0; acc[5] = bf_hi(su.z) * d0;
        acc[6] = bf_lo(su.w) * d0; acc[7] = bf_hi(su.w) * d0;
    }

    uint2 inf = nodeinfo[node];
    int beg = (int)inf.x, end = beg + (int)inf.y;
    for (int j = beg; j < end; j += 64) {
        int cs = 0; float cw = 0.f;
        if (j + lane < end) {
            uint2 p = csr[j + lane];
            cs = (int)p.x;
            cw = __uint_as_float(p.y) * dinv[cs];
        }
        int mm = end - j; if (mm > 64) mm = 64;
#pragma unroll 2
        for (int k = 0; k < mm; k += 8) {
            int   s = __shfl(cs, k + q);
            float w = __shfl(cw, k + q);
            uint4 u = Hb4[(size_t)s * 8 + cg];
            acc[0] = fmaf(bf_lo(u.x), w, acc[0]); acc[1] = fmaf(bf_hi(u.x), w, acc[1]);
            acc[2] = fmaf(bf_lo(u.y), w, acc[2]); acc[3] = fmaf(bf_hi(u.y), w, acc[3]);
            acc[4] = fmaf(bf_lo(u.z), w, acc[4]); acc[5] = fmaf(bf_hi(u.z), w, acc[5]);
            acc[6] = fmaf(bf_lo(u.w), w, acc[6]); acc[7] = fmaf(bf_hi(u.w), w, acc[7]);
        }
    }

#pragma unroll
    for (int v = 0; v < 8; ++v) {
        acc[v] += __shfl_xor(acc[v], 8);
        acc[v] += __shfl_xor(acc[v], 16);
        acc[v] += __shfl_xor(acc[v], 32);
    }

    int c = cg * 8 + q;
    OUT[(size_t)node * 64 + c] = acc[q] * di + bias[c];
}

static inline size_t align_up(size_t x) { return (x + 255) & ~size_t(255); }

extern "C" void kernel_launch(void* const* d_in, const int* in_sizes, int n_in,
                              void* d_out, int out_size, void* d_ws, size_t ws_size,
                              hipStream_t stream)
{
    const float* x  = (const float*)d_in[0];
    const int*   ei = (const int*)d_in[1];
    const float* ew = (const float*)d_in[2];
    const float* W1 = (const float*)d_in[3];
    const float* b1 = (const float*)d_in[4];
    const float* W2 = (const float*)d_in[5];
    const float* b2 = (const float*)d_in[6];
    float* out = (float*)d_out;

    const int N = N_NODES;
    const int E = in_sizes[2];
    const int* src = ei;
    const int* dst = ei + E;

    const int NBLK = (E + CHUNK - 1) / CHUNK;
    const size_t REGION = (size_t)NBUCK * CAP;
    const int GEMM1B = (N + 63) / 64;

    char* ws = (char*)d_ws;
    int*   histmat   = (int*)ws;   ws += align_up((size_t)NBLK * 256 * 4);
    int*   bucketSize= (int*)ws;   ws += align_up((size_t)NBUCK * 4);
    float* dinv      = (float*)ws; ws += align_up((size_t)N * 4);
    uint2* nodeinfo  = (uint2*)ws; ws += align_up((size_t)N * 8);
    uint2* csrTmp    = (uint2*)ws; ws += align_up(REGION * 8);
    uint2* csrF      = (uint2*)ws; ws += align_up(REGION * 8);
    unsigned* Wt1    = (unsigned*)ws; ws += align_up((size_t)128 * 64 * 4);
    unsigned* Wt2    = (unsigned*)ws; ws += align_up((size_t)64 * 64 * 4);
    unsigned* h1     = (unsigned*)ws; ws += align_up((size_t)N * 64 * 4);  // bf16 pk
    unsigned* h2     = (unsigned*)ws; ws += align_up((size_t)N * 32 * 4);  // bf16 pk

    // 1: W-pack + histogram
    prepA1_kernel<<<NBLK + 2, 256, 0, stream>>>(dst, W1, W2, Wt1, Wt2, histmat, E);
    // 2: bucket scan
    scanB_kernel<<<NBUCK, 256, 0, stream>>>(histmat, bucketSize, NBLK);
    // 3: A2 reorder + gemm1 (overlapped in one dispatch)
    a2_gemm_kernel<<<NBLK + GEMM1B, 256, 0, stream>>>(
        src, dst, ew, histmat, csrTmp, E, NBLK, x, Wt1, h1, N);
    // 4: per-bucket dinv/nodeinfo/sort
    bucketB_kernel<<<NBUCK, 1024, 0, stream>>>(csrTmp, bucketSize, dinv, nodeinfo, csrF, N);
    // 5: gather128 + gemm2 fused
    gg_kernel<<<N / 16, 256, 0, stream>>>(nodeinfo, csrF, (const uint4*)h1,
                                          dinv, b1, Wt2, h2, N);
    // 6: gather64
    gather64_kernel<<<(N + 3) / 4, 256, 0, stream>>>(
        nodeinfo, csrF, (const uint4*)h2, dinv, b2, out, N);
}

// Round 9
// 282.484 us; speedup vs baseline: 15.4242x; 1.0233x over previous
//
#include <hip/hip_runtime.h>

// ---------------------------------------------------------------------------
// Two-layer GCN on MI355X.  Round 9: dinv folded into feature rows.
//   hs = dinv[r]*(x@W1)  =>  out1[d] = dinv[d]*(sum_e ew*hs[s] + hs[d]) + b1
//   -> gather edge weight is PURE ew (no per-edge dinv load, the R8 regression)
//   Pipeline (7 dispatches):
//     1. prepA1  : W1/W2 bf16 B-layout pack + per-block dst histogram
//     2. scanB   : per-bucket scan over blocks
//     3. a2      : bucket-reorder edges -> csrTmp
//     4. bucketB : per-bucket dinv, nodeinfo, node-sorted csrF={s,ew}
//     5. gemm1   : h1s = dinv*(x@W1)  (MFMA, row-scaled epilogue)
//     6. gg      : gather(ew) + bias/relu + MFMA gemm2, h2s = dinv*h2
//     7. gather64: gather(ew) + final scale + bias -> out fp32
// ---------------------------------------------------------------------------

#define N_NODES 100000
#define CHUNK   2048
#define NBUCK   196
#define BSHIFT  9
#define BNODES  512
#define CAP     10240

typedef __attribute__((ext_vector_type(8))) short bf16x8;
typedef __attribute__((ext_vector_type(4))) float f32x4;

__device__ __forceinline__ unsigned bf16r(float f) {
    unsigned u = __float_as_uint(f);
    return (u + 0x7fffu + ((u >> 16) & 1u)) >> 16;     // RNE
}
__device__ __forceinline__ float bf_lo(unsigned u) { return __uint_as_float(u << 16); }
__device__ __forceinline__ float bf_hi(unsigned u) { return __uint_as_float(u & 0xffff0000u); }

// ---- 1. prepA1: W-pack (blocks 0,1) + per-block bucket histogram ----------

__global__ __launch_bounds__(256) void prepA1_kernel(
    const int* __restrict__ dst, const float* __restrict__ W1,
    const float* __restrict__ W2, unsigned* __restrict__ Wt1,
    unsigned* __restrict__ Wt2, int* __restrict__ histmat, int E)
{
    __shared__ int hist[256];
    int t = threadIdx.x;
    if (blockIdx.x == 0) {
        for (int f = t; f < 128 * 64; f += 256) {
            int c = f % 128, j = f / 128;
            Wt1[c * 64 + j] = bf16r(W1[(size_t)(2 * j) * 128 + c]) |
                              (bf16r(W1[(size_t)(2 * j + 1) * 128 + c]) << 16);
        }
        return;
    }
    if (blockIdx.x == 1) {
        for (int f = t; f < 64 * 64; f += 256) {
            int c = f % 64, j = f / 64;
            Wt2[c * 64 + j] = bf16r(W2[(size_t)(2 * j) * 64 + c]) |
                              (bf16r(W2[(size_t)(2 * j + 1) * 64 + c]) << 16);
        }
        return;
    }
    int blk = blockIdx.x - 2;
    hist[t] = 0;
    __syncthreads();
    int e0 = blk * CHUNK;
    int nv = min(CHUNK, E - e0);
#pragma unroll
    for (int j = 0; j < CHUNK / 256; ++j) {
        int idx = t + j * 256;
        if (idx < nv) atomicAdd(&hist[dst[e0 + idx] >> BSHIFT], 1);
    }
    __syncthreads();
    histmat[blk * 256 + t] = hist[t];
}

// ---- 2. scanB -------------------------------------------------------------

__global__ __launch_bounds__(256) void scanB_kernel(
    int* __restrict__ histmat, int* __restrict__ bucketSize, int NBLK)
{
    __shared__ int sums[256];
    int b = blockIdx.x, t = threadIdx.x;
    const int PER = (NBLK + 255) / 256;
    int loc[8];
    int s = 0;
#pragma unroll 8
    for (int j = 0; j < PER; ++j) {
        int r = t * PER + j;
        int v = (r < NBLK) ? histmat[r * 256 + b] : 0;
        loc[j] = v; s += v;
    }
    sums[t] = s;
    __syncthreads();
    int v = s;
#pragma unroll
    for (int off = 1; off < 256; off <<= 1) {
        int a = (t >= off) ? sums[t - off] : 0;
        __syncthreads();
        sums[t] += a;
        __syncthreads();
    }
    if (t == 255) bucketSize[b] = sums[255];
    int run = sums[t] - v;
#pragma unroll 8
    for (int j = 0; j < PER; ++j) {
        int r = t * PER + j;
        if (r < NBLK) { histmat[r * 256 + b] = run; run += loc[j]; }
    }
}

// ---- 3. a2: reorder block's edges by bucket, write grouped runs -----------

__global__ __launch_bounds__(256) void a2_kernel(
    const int* __restrict__ src, const int* __restrict__ dst,
    const float* __restrict__ ew, const int* __restrict__ histmat,
    uint2* __restrict__ csrTmp, int E)
{
    __shared__ int hist[256], sc[256], exc[256], lcur[256], basel[256];
    __shared__ uint2 ent[CHUNK];
    __shared__ unsigned short bof[CHUNK];

    int t = threadIdx.x, blk = blockIdx.x;
    hist[t] = 0; lcur[t] = 0;
    basel[t] = histmat[blk * 256 + t];
    __syncthreads();

    int e0 = blk * CHUNK;
    int nv = min(CHUNK, E - e0);
    int dv[CHUNK / 256]; int sv[CHUNK / 256]; unsigned wv[CHUNK / 256];
#pragma unroll
    for (int j = 0; j < CHUNK / 256; ++j) {
        int idx = t + j * 256;
        if (idx < nv) {
            int e = e0 + idx;
            dv[j] = dst[e]; sv[j] = src[e]; wv[j] = __float_as_uint(ew[e]);
            atomicAdd(&hist[dv[j] >> BSHIFT], 1);
        } else dv[j] = -1;
    }
    __syncthreads();
    int hv = hist[t];
    sc[t] = hv;
    __syncthreads();
#pragma unroll
    for (int off = 1; off < 256; off <<= 1) {
        int a = (t >= off) ? sc[t - off] : 0;
        __syncthreads();
        sc[t] += a;
        __syncthreads();
    }
    exc[t] = sc[t] - hv;
    __syncthreads();
#pragma unroll
    for (int j = 0; j < CHUNK / 256; ++j) {
        if (dv[j] >= 0) {
            int b  = dv[j] >> BSHIFT;
            int dl = dv[j] & (BNODES - 1);
            int p  = exc[b] + atomicAdd(&lcur[b], 1);
            ent[p] = make_uint2(((unsigned)dl << 17) | (unsigned)sv[j], wv[j]);
            bof[p] = (unsigned short)b;
        }
    }
    __syncthreads();
#pragma unroll
    for (int j = 0; j < CHUNK / 256; ++j) {
        int i = t + j * 256;
        if (i < nv) {
            int b = bof[i];
            csrTmp[(size_t)b * CAP + basel[b] + (i - exc[b])] = ent[i];
        }
    }
}

// ---- 4. bucketB: dinv, nodeinfo, node-sorted csrF={s,ew} ------------------

__global__ __launch_bounds__(1024) void bucketB_kernel(
    const uint2* __restrict__ csrTmp, const int* __restrict__ bucketSize,
    float* __restrict__ dinv, uint2* __restrict__ nodeinfo,
    uint2* __restrict__ csrF, int N)
{
    __shared__ uint2 ent[CAP];
    __shared__ unsigned long long dc[BNODES];
    __shared__ int scn[BNODES], beg[BNODES], cur[BNODES];
    int b = blockIdx.x, t = threadIdx.x;
    if (t < BNODES) { dc[t] = 0ull; cur[t] = 0; }
    __syncthreads();

    int sz = min(bucketSize[b], CAP);
    const uint2* reg = csrTmp + (size_t)b * CAP;
    for (int i = t; i < sz; i += 1024) {
        uint2 en = reg[i];
        ent[i] = en;
        int dl = (int)(en.x >> 17);
        unsigned fx = (unsigned)__float2uint_rn(__uint_as_float(en.y) * 16777216.0f);
        atomicAdd(&dc[dl], (1ull << 32) | (unsigned long long)fx);
    }
    __syncthreads();

    int cnt = 0; float dv = 1.0f;
    if (t < BNODES) {
        unsigned long long v = dc[t];
        cnt = (int)(v >> 32);
        dv = rsqrtf((float)(unsigned)(v & 0xffffffffull) * (1.0f / 16777216.0f) + 1.0f);
        scn[t] = cnt;
    }
    __syncthreads();
#pragma unroll
    for (int off = 1; off < BNODES; off <<= 1) {
        int a = 0;
        if (t < BNODES && t >= off) a = scn[t - off];
        __syncthreads();
        if (t < BNODES) scn[t] += a;
        __syncthreads();
    }
    if (t < BNODES) {
        int excl = scn[t] - cnt;
        beg[t] = excl;
        int gn = b * BNODES + t;
        if (gn < N) {
            dinv[gn] = dv;
            nodeinfo[gn] = make_uint2((unsigned)(b * CAP + excl), (unsigned)cnt);
        }
    }
    __syncthreads();

    uint2* outreg = csrF + (size_t)b * CAP;
    for (int i = t; i < sz; i += 1024) {
        uint2 en = ent[i];
        int dl = (int)(en.x >> 17);
        int p  = beg[dl] + atomicAdd(&cur[dl], 1);
        outreg[p] = make_uint2(en.x & 0x1FFFFu, en.y);   // {src, ew}
    }
}

// ---- 5. gemm1: h1s = dinv * (x @ W1), bf16-packed -------------------------

__global__ __launch_bounds__(256) void gemm1_kernel(
    const float* __restrict__ Xf, const unsigned* __restrict__ Wt,
    const float* __restrict__ dinv, unsigned* __restrict__ Hb, int M)
{
    constexpr int LW = 68, KU = 64;
    __shared__ unsigned sA[64 * LW];
    __shared__ unsigned sB[128 * LW];
    __shared__ float sD[64];
    const int t = threadIdx.x;
    const int rbase = blockIdx.x * 64;

    if (t < 64) sD[t] = (rbase + t < M) ? dinv[rbase + t] : 0.f;
    for (int f = t; f < 128 * 16; f += 256) {       // B: 128 rows x 16 uint4
        int c = f >> 4, qd = f & 15;
        *(uint4*)&sB[c * LW + qd * 4] = *(const uint4*)&Wt[c * KU + qd * 4];
    }
    for (int f = t; f < 64 * 32; f += 256) {        // A: fp32 -> bf16 pack
        int r = f >> 5, c4 = f & 31;
        int gr = rbase + r;
        float4 v = make_float4(0.f, 0.f, 0.f, 0.f);
        if (gr < M) v = *(const float4*)&Xf[(size_t)gr * 128 + c4 * 4];
        sA[r * LW + c4 * 2]     = bf16r(v.x) | (bf16r(v.y) << 16);
        sA[r * LW + c4 * 2 + 1] = bf16r(v.z) | (bf16r(v.w) << 16);
    }
    __syncthreads();

    const int wave = t >> 6, lane = t & 63;
    const int quad = lane >> 4, lr = lane & 15;
    const int n0 = wave * 32;

    f32x4 acc[4][2];
#pragma unroll
    for (int mi = 0; mi < 4; ++mi)
#pragma unroll
        for (int ni = 0; ni < 2; ++ni)
            acc[mi][ni] = (f32x4){0.f, 0.f, 0.f, 0.f};

#pragma unroll
    for (int ks = 0; ks < 4; ++ks) {
        int ko = ks * 16 + quad * 4;
        bf16x8 b0 = *(const bf16x8*)&sB[(n0 + lr) * LW + ko];
        bf16x8 b1 = *(const bf16x8*)&sB[(n0 + 16 + lr) * LW + ko];
#pragma unroll
        for (int mi = 0; mi < 4; ++mi) {
            bf16x8 a = *(const bf16x8*)&sA[(mi * 16 + lr) * LW + ko];
            acc[mi][0] = __builtin_amdgcn_mfma_f32_16x16x32_bf16(a, b0, acc[mi][0], 0, 0, 0);
            acc[mi][1] = __builtin_amdgcn_mfma_f32_16x16x32_bf16(a, b1, acc[mi][1], 0, 0, 0);
        }
    }
    __syncthreads();

    unsigned short* sO = (unsigned short*)sA;       // [64][2*LW]
#pragma unroll
    for (int mi = 0; mi < 4; ++mi)
#pragma unroll
        for (int ni = 0; ni < 2; ++ni)
#pragma unroll
            for (int r = 0; r < 4; ++r) {
                int row = mi * 16 + quad * 4 + r;
                sO[row * (2 * LW) + n0 + ni * 16 + lr] =
                    (unsigned short)bf16r(acc[mi][ni][r] * sD[row]);
            }
    __syncthreads();

    for (int f = t; f < 64 * 64; f += 256) {
        int row = f >> 6, cu = f & 63;
        int gr = rbase + row;
        if (gr < M) Hb[(size_t)gr * 64 + cu] = sA[row * LW + cu];
    }
}

// ---- 6. gg: gather h1s (+scale+bias+relu) + MFMA gemm2, h2s row-scaled ----
// 512 thr / 8 waves, 16 nodes (2 per wave).  Edge weight = pure ew.

__global__ __launch_bounds__(512) void gg_kernel(
    const uint2* __restrict__ nodeinfo, const uint2* __restrict__ csr,
    const uint4* __restrict__ Hb4,                 // h1s row = 16 uint4
    const float* __restrict__ dinv, const float* __restrict__ bias,
    const unsigned* __restrict__ Wt2, unsigned* __restrict__ H2, int N)
{
    __shared__ __align__(16) unsigned sG[16 * 68];   // g1 tile bf16-packed
    __shared__ __align__(16) float    sO[16 * 68];   // h2 fp32 tile
    __shared__ float sDi[16];

    const int t = threadIdx.x, wave = t >> 6, lane = t & 63;
    const int q = lane >> 4, cg = lane & 15;
    const int nb = blockIdx.x * 16;
    if (t < 16) sDi[t] = dinv[nb + t];

    for (int i = 0; i < 2; ++i) {
        int m = wave * 2 + i;
        int node = nb + m;                 // 6250*16 == 100000: no tail
        float one0 = (q == 0) ? 1.f : 0.f; // self-loop weight 1 (hs carries dinv)
        float acc[8];
        {
            uint4 su = Hb4[(size_t)node * 16 + cg];
            acc[0] = bf_lo(su.x) * one0; acc[1] = bf_hi(su.x) * one0;
            acc[2] = bf_lo(su.y) * one0; acc[3] = bf_hi(su.y) * one0;
            acc[4] = bf_lo(su.z) * one0; acc[5] = bf_hi(su.z) * one0;
            acc[6] = bf_lo(su.w) * one0; acc[7] = bf_hi(su.w) * one0;
        }
        uint2 inf = nodeinfo[node];
        int beg = (int)inf.x, end = beg + (int)inf.y;
        for (int j = beg; j < end; j += 64) {
            int cs = 0; float cw = 0.f;
            if (j + lane < end) {
                uint2 p = csr[j + lane];
                cs = (int)p.x;
                cw = __uint_as_float(p.y);          // pure ew
            }
            int mm = end - j; if (mm > 64) mm = 64;
#pragma unroll 4
            for (int k = 0; k < mm; k += 4) {
                int   s = __shfl(cs, k + q);
                float w = __shfl(cw, k + q);        // 0 beyond mm
                uint4 u = Hb4[(size_t)s * 16 + cg];
                acc[0] = fmaf(bf_lo(u.x), w, acc[0]); acc[1] = fmaf(bf_hi(u.x), w, acc[1]);
                acc[2] = fmaf(bf_lo(u.y), w, acc[2]); acc[3] = fmaf(bf_hi(u.y), w, acc[3]);
                acc[4] = fmaf(bf_lo(u.z), w, acc[4]); acc[5] = fmaf(bf_hi(u.z), w, acc[5]);
                acc[6] = fmaf(bf_lo(u.w), w, acc[6]); acc[7] = fmaf(bf_hi(u.w), w, acc[7]);
            }
        }
#pragma unroll
        for (int v = 0; v < 8; ++v) {
            acc[v] += __shfl_xor(acc[v], 16);
            acc[v] += __shfl_xor(acc[v], 32);
        }
        if (q == 0) {
            float di = dinv[node];
            int c = cg * 8;
            uint4 pk;
            pk.x = bf16r(fmaxf(acc[0] * di + bias[c + 0], 0.f)) |
                   (bf16r(fmaxf(acc[1] * di + bias[c + 1], 0.f)) << 16);
            pk.y = bf16r(fmaxf(acc[2] * di + bias[c + 2], 0.f)) |
                   (bf16r(fmaxf(acc[3] * di + bias[c + 3], 0.f)) << 16);
            pk.z = bf16r(fmaxf(acc[4] * di + bias[c + 4], 0.f)) |
                   (bf16r(fmaxf(acc[5] * di + bias[c + 5], 0.f)) << 16);
            pk.w = bf16r(fmaxf(acc[6] * di + bias[c + 6], 0.f)) |
                   (bf16r(fmaxf(acc[7] * di + bias[c + 7], 0.f)) << 16);
            *(uint4*)&sG[m * 68 + cg * 4] = pk;
        }
    }
    __syncthreads();

    // h2 tile: waves 0..3 each compute n-tile n0 = wave*16
    if (wave < 4) {
        const int quad = lane >> 4, lr = lane & 15;
        const int n0 = wave * 16;
        f32x4 accv = (f32x4){0.f, 0.f, 0.f, 0.f};
#pragma unroll
        for (int ks = 0; ks < 4; ++ks) {
            int ko = ks * 16 + quad * 4;
            bf16x8 av = *(const bf16x8*)&sG[lr * 68 + ko];
            bf16x8 bv = *(const bf16x8*)&Wt2[(n0 + lr) * 64 + ko];
            accv = __builtin_amdgcn_mfma_f32_16x16x32_bf16(av, bv, accv, 0, 0, 0);
        }
#pragma unroll
        for (int r = 0; r < 4; ++r)
            sO[(quad * 4 + r) * 68 + n0 + lr] = accv[r];
    }
    __syncthreads();

    if (t < 512) {                         // 16 rows x 32 packed uints
        int row = t >> 5, cu = t & 31;
        float sc = sDi[row];               // h2s = dinv * h2
        unsigned pk = bf16r(sO[row * 68 + 2 * cu] * sc) |
                      (bf16r(sO[row * 68 + 2 * cu + 1] * sc) << 16);
        H2[(size_t)(nb + row) * 32 + cu] = pk;
    }
}

// ---- 7. gather64: aggregate h2s -> out fp32 -------------------------------

__global__ __launch_bounds__(256) void gather64_kernel(
    const uint2* __restrict__ nodeinfo, const uint2* __restrict__ csr,
    const uint4* __restrict__ Hb4,                 // h2s row = 8 uint4
    const float* __restrict__ dinv, const float* __restrict__ bias,
    float* __restrict__ OUT, int N)
{
    int node = blockIdx.x * 4 + (threadIdx.x >> 6);
    if (node >= N) return;
    int lane = threadIdx.x & 63;
    int q  = lane >> 3;        // slot 0..7
    int cg = lane & 7;

    float one0 = (q == 0) ? 1.f : 0.f;
    float acc[8];
    {
        uint4 su = Hb4[(size_t)node * 8 + cg];
        acc[0] = bf_lo(su.x) * one0; acc[1] = bf_hi(su.x) * one0;
        acc[2] = bf_lo(su.y) * one0; acc[3] = bf_hi(su.y) * one0;
        acc[4] = bf_lo(su.z) * one0; acc[5] = bf_hi(su.z) * one0;
        acc[6] = bf_lo(su.w) * one0; acc[7] = bf_hi(su.w) * one0;
    }

    uint2 inf = nodeinfo[node];
    int beg = (int)inf.x, end = beg + (int)inf.y;
    for (int j = beg; j < end; j += 64) {
        int cs = 0; float cw = 0.f;
        if (j + lane < end) {
            uint2 p = csr[j + lane];
            cs = (int)p.x;
            cw = __uint_as_float(p.y);             // pure ew
        }
        int mm = end - j; if (mm > 64) mm = 64;
#pragma unroll 2
        for (int k = 0; k < mm; k += 8) {
            int   s = __shfl(cs, k + q);
            float w = __shfl(cw, k + q);
            uint4 u = Hb4[(size_t)s * 8 + cg];
            acc[0] = fmaf(bf_lo(u.x), w, acc[0]); acc[1] = fmaf(bf_hi(u.x), w, acc[1]);
            acc[2] = fmaf(bf_lo(u.y), w, acc[2]); acc[3] = fmaf(bf_hi(u.y), w, acc[3]);
            acc[4] = fmaf(bf_lo(u.z), w, acc[4]); acc[5] = fmaf(bf_hi(u.z), w, acc[5]);
            acc[6] = fmaf(bf_lo(u.w), w, acc[6]); acc[7] = fmaf(bf_hi(u.w), w, acc[7]);
        }
    }

#pragma unroll
    for (int v = 0; v < 8; ++v) {
        acc[v] += __shfl_xor(acc[v], 8);
        acc[v] += __shfl_xor(acc[v], 16);
        acc[v] += __shfl_xor(acc[v], 32);
    }

    int c = cg * 8 + q;
    OUT[(size_t)node * 64 + c] = acc[q] * dinv[node] + bias[c];
}

static inline size_t align_up(size_t x) { return (x + 255) & ~size_t(255); }

extern "C" void kernel_launch(void* const* d_in, const int* in_sizes, int n_in,
                              void* d_out, int out_size, void* d_ws, size_t ws_size,
                              hipStream_t stream)
{
    const float* x  = (const float*)d_in[0];
    const int*   ei = (const int*)d_in[1];
    const float* ew = (const float*)d_in[2];
    const float* W1 = (const float*)d_in[3];
    const float* b1 = (const float*)d_in[4];
    const float* W2 = (const float*)d_in[5];
    const float* b2 = (const float*)d_in[6];
    float* out = (float*)d_out;

    const int N = N_NODES;
    const int E = in_sizes[2];
    const int* src = ei;
    const int* dst = ei + E;

    const int NBLK = (E + CHUNK - 1) / CHUNK;
    const size_t REGION = (size_t)NBUCK * CAP;

    char* ws = (char*)d_ws;
    int*   histmat   = (int*)ws;   ws += align_up((size_t)NBLK * 256 * 4);
    int*   bucketSize= (int*)ws;   ws += align_up((size_t)NBUCK * 4);
    float* dinv      = (float*)ws; ws += align_up((size_t)N * 4);
    uint2* nodeinfo  = (uint2*)ws; ws += align_up((size_t)N * 8);
    uint2* csrTmp    = (uint2*)ws; ws += align_up(REGION * 8);
    uint2* csrF      = (uint2*)ws; ws += align_up(REGION * 8);
    unsigned* Wt1    = (unsigned*)ws; ws += align_up((size_t)128 * 64 * 4);
    unsigned* Wt2    = (unsigned*)ws; ws += align_up((size_t)64 * 64 * 4);
    unsigned* h1     = (unsigned*)ws; ws += align_up((size_t)N * 64 * 4);  // h1s bf16 pk
    unsigned* h2     = (unsigned*)ws; ws += align_up((size_t)N * 32 * 4);  // h2s bf16 pk

    prepA1_kernel<<<NBLK + 2, 256, 0, stream>>>(dst, W1, W2, Wt1, Wt2, histmat, E);
    scanB_kernel<<<NBUCK, 256, 0, stream>>>(histmat, bucketSize, NBLK);
    a2_kernel<<<NBLK, 256, 0, stream>>>(src, dst, ew, histmat, csrTmp, E);
    bucketB_kernel<<<NBUCK, 1024, 0, stream>>>(csrTmp, bucketSize, dinv, nodeinfo, csrF, N);
    gemm1_kernel<<<(N + 63) / 64, 256, 0, stream>>>(x, Wt1, dinv, h1, N);
    gg_kernel<<<N / 16, 512, 0, stream>>>(nodeinfo, csrF, (const uint4*)h1,
                                          dinv, b1, Wt2, h2, N);
    gather64_kernel<<<(N + 3) / 4, 256, 0, stream>>>(
        nodeinfo, csrF, (const uint4*)h2, dinv, b2, out, N);
}